// Round 1
// baseline (425.516 us; speedup 1.0000x reference)
//
#include <hip/hip_runtime.h>

#define IN_DIM 256
#define OUT_DIM 64
#define NEG_SLOPE 0.01f

// ---- monotone float <-> uint encoding for atomicMax on floats ----
__device__ __forceinline__ unsigned enc_f32(float f) {
    unsigned u = __float_as_uint(f);
    return (u & 0x80000000u) ? ~u : (u | 0x80000000u);
}
__device__ __forceinline__ float dec_f32(unsigned v) {
    unsigned u = (v & 0x80000000u) ? (v ^ 0x80000000u) : ~v;
    return __uint_as_float(u);
}

// K0: zero-init output, segment sums, segment max encodings (harness poisons buffers).
__global__ void k0_init(float* __restrict__ out, float* __restrict__ ssum,
                        unsigned* __restrict__ menc, int N) {
    int idx = blockIdx.x * blockDim.x + threadIdx.x;
    int total = N * OUT_DIM;
    if (idx < total) out[idx] = 0.0f;
    if (idx < N) { ssum[idx] = 0.0f; menc[idx] = 0u; }
}

// K1: z = h @ W^T  (+ fused el = z@a_l, er = z@a_r)
// One wave per 8-row group; lane o owns output column o.
__global__ __launch_bounds__(256) void k1_proj(
        const float* __restrict__ h, const float* __restrict__ W,
        const float* __restrict__ a,
        float* __restrict__ z, float* __restrict__ el, float* __restrict__ er,
        int N) {
    const int lane = threadIdx.x & 63;
    const int wave = threadIdx.x >> 6;
    const int group = blockIdx.x * 4 + wave;       // 8-row group id
    const int r0 = group * 8;
    if (r0 >= N) return;

    const float al = a[lane];
    const float ar = a[OUT_DIM + lane];
    const float* __restrict__ wrow = W + (size_t)lane * IN_DIM;

    const float* hp[8];
    #pragma unroll
    for (int r = 0; r < 8; ++r) {
        int rr = r0 + r; if (rr > N - 1) rr = N - 1;   // clamp (N%8==0 so unused)
        hp[r] = h + (size_t)rr * IN_DIM;
    }

    float acc[8];
    #pragma unroll
    for (int r = 0; r < 8; ++r) acc[r] = 0.0f;

    for (int k4 = 0; k4 < IN_DIM / 4; ++k4) {
        float4 w4 = *(const float4*)(wrow + k4 * 4);
        #pragma unroll
        for (int r = 0; r < 8; ++r) {
            float4 h4 = *(const float4*)(hp[r] + k4 * 4);   // wave-broadcast
            acc[r] += h4.x * w4.x + h4.y * w4.y + h4.z * w4.z + h4.w * w4.w;
        }
    }

    #pragma unroll
    for (int r = 0; r < 8; ++r) {
        int row = r0 + r;
        bool ok = (row < N);
        if (ok) z[(size_t)row * OUT_DIM + lane] = acc[r];
        float vl = acc[r] * al;
        float vr = acc[r] * ar;
        #pragma unroll
        for (int m = 32; m >= 1; m >>= 1) {
            vl += __shfl_xor(vl, m, 64);
            vr += __shfl_xor(vr, m, 64);
        }
        if (ok && lane == 0) { el[row] = vl; er[row] = vr; }
    }
}

// K2: per-edge logit e = leaky_relu(el[src]+er[dst]); segment max into menc[dst]
__global__ void k2_edge_max(const int* __restrict__ src, const int* __restrict__ dst,
                            const float* __restrict__ el, const float* __restrict__ er,
                            float* __restrict__ ebuf, unsigned* __restrict__ menc, int E) {
    int i = blockIdx.x * blockDim.x + threadIdx.x;
    if (i >= E) return;
    int s = src[i], d = dst[i];
    float x = el[s] + er[d];
    float e = (x > 0.0f) ? x : NEG_SLOPE * x;
    ebuf[i] = e;
    atomicMax(menc + d, enc_f32(e));
}

// K3: ex = exp(e - m[dst]); segment sum into ssum[dst]; overwrite ebuf with ex
__global__ void k3_edge_exp(const int* __restrict__ dst,
                            float* __restrict__ ebuf, const unsigned* __restrict__ menc,
                            float* __restrict__ ssum, int E) {
    int i = blockIdx.x * blockDim.x + threadIdx.x;
    if (i >= E) return;
    int d = dst[i];
    float m = dec_f32(menc[d]);
    float ex = __expf(ebuf[i] - m);
    ebuf[i] = ex;
    atomicAdd(ssum + d, ex);
}

// K4: one wave per edge; lane o scatters alpha * z[src][o] into out[dst][o]
__global__ __launch_bounds__(256) void k4_agg(
        const int* __restrict__ src, const int* __restrict__ dst,
        const float* __restrict__ ebuf, const float* __restrict__ ssum,
        const float* __restrict__ z, float* __restrict__ out, int E) {
    const int lane = threadIdx.x & 63;
    const int eid = blockIdx.x * 4 + (threadIdx.x >> 6);
    if (eid >= E) return;
    int s = src[eid], d = dst[eid];
    float alpha = ebuf[eid] / ssum[d];
    float v = alpha * z[(size_t)s * OUT_DIM + lane];
    atomicAdd(out + (size_t)d * OUT_DIM + lane, v);
}

extern "C" void kernel_launch(void* const* d_in, const int* in_sizes, int n_in,
                              void* d_out, int out_size, void* d_ws, size_t ws_size,
                              hipStream_t stream) {
    const float* h   = (const float*)d_in[0];
    const float* W   = (const float*)d_in[1];
    const float* a   = (const float*)d_in[2];
    const int*   src = (const int*)d_in[3];
    const int*   dst = (const int*)d_in[4];
    float* out = (float*)d_out;

    const int N = in_sizes[0] / IN_DIM;     // 50000
    const int E = in_sizes[3];              // 800000

    // workspace layout (floats)
    float* z    = (float*)d_ws;             // N*64
    float* el   = z + (size_t)N * OUT_DIM;  // N
    float* er   = el + N;                   // N
    float* ebuf = er + N;                   // E
    float* ssum = ebuf + E;                 // N
    unsigned* menc = (unsigned*)(ssum + N); // N

    {
        int total = N * OUT_DIM;
        int grid = (total + 255) / 256;
        k0_init<<<grid, 256, 0, stream>>>(out, ssum, menc, N);
    }
    {
        int groups = (N + 7) / 8;
        int grid = (groups + 3) / 4;
        k1_proj<<<grid, 256, 0, stream>>>(h, W, a, z, el, er, N);
    }
    {
        int grid = (E + 255) / 256;
        k2_edge_max<<<grid, 256, 0, stream>>>(src, dst, el, er, ebuf, menc, E);
        k3_edge_exp<<<grid, 256, 0, stream>>>(dst, ebuf, menc, ssum, E);
    }
    {
        int grid = (E + 3) / 4;
        k4_agg<<<grid, 256, 0, stream>>>(src, dst, ebuf, ssum, z, out, E);
    }
}

// Round 2
// 314.175 us; speedup vs baseline: 1.3544x; 1.3544x over previous
//
#include <hip/hip_runtime.h>

#define IN_DIM 256
#define OUT_DIM 64
#define NEG_SLOPE 0.01f

// ---------------- K0: zero the histogram ----------------
__global__ void k_zero(int* __restrict__ counts, int N) {
    int i = blockIdx.x * blockDim.x + threadIdx.x;
    if (i < N) counts[i] = 0;
}

// ---------------- K1: z = h @ W^T (+ fused el = z@a_l, er = z@a_r) ----------
// One wave per 8-row group; lane o owns output column o. (unchanged from R0)
__global__ __launch_bounds__(256) void k1_proj(
        const float* __restrict__ h, const float* __restrict__ W,
        const float* __restrict__ a,
        float* __restrict__ z, float* __restrict__ el, float* __restrict__ er,
        int N) {
    const int lane = threadIdx.x & 63;
    const int wave = threadIdx.x >> 6;
    const int group = blockIdx.x * 4 + wave;       // 8-row group id
    const int r0 = group * 8;
    if (r0 >= N) return;

    const float al = a[lane];
    const float ar = a[OUT_DIM + lane];
    const float* __restrict__ wrow = W + (size_t)lane * IN_DIM;

    const float* hp[8];
    #pragma unroll
    for (int r = 0; r < 8; ++r) {
        int rr = r0 + r; if (rr > N - 1) rr = N - 1;
        hp[r] = h + (size_t)rr * IN_DIM;
    }

    float acc[8];
    #pragma unroll
    for (int r = 0; r < 8; ++r) acc[r] = 0.0f;

    for (int k4 = 0; k4 < IN_DIM / 4; ++k4) {
        float4 w4 = *(const float4*)(wrow + k4 * 4);
        #pragma unroll
        for (int r = 0; r < 8; ++r) {
            float4 h4 = *(const float4*)(hp[r] + k4 * 4);   // wave-broadcast
            acc[r] += h4.x * w4.x + h4.y * w4.y + h4.z * w4.z + h4.w * w4.w;
        }
    }

    #pragma unroll
    for (int r = 0; r < 8; ++r) {
        int row = r0 + r;
        bool ok = (row < N);
        if (ok) z[(size_t)row * OUT_DIM + lane] = acc[r];
        float vl = acc[r] * al;
        float vr = acc[r] * ar;
        #pragma unroll
        for (int m = 32; m >= 1; m >>= 1) {
            vl += __shfl_xor(vl, m, 64);
            vr += __shfl_xor(vr, m, 64);
        }
        if (ok && lane == 0) { el[row] = vl; er[row] = vr; }
    }
}

// ---------------- K2: histogram of dst ----------------
__global__ void k_hist(const int* __restrict__ dst, int* __restrict__ counts, int E) {
    int i = blockIdx.x * blockDim.x + threadIdx.x;
    if (i < E) atomicAdd(counts + dst[i], 1);
}

// ---------------- K3: 3-phase exclusive scan over counts (in place) --------
__global__ void k_scanA(const int* __restrict__ counts, int* __restrict__ bsum, int N) {
    __shared__ int sm[256];
    int i = blockIdx.x * 256 + threadIdx.x;
    sm[threadIdx.x] = (i < N) ? counts[i] : 0;
    __syncthreads();
    for (int off = 128; off; off >>= 1) {
        if (threadIdx.x < off) sm[threadIdx.x] += sm[threadIdx.x + off];
        __syncthreads();
    }
    if (threadIdx.x == 0) bsum[blockIdx.x] = sm[0];
}

__global__ void k_scanB(int* __restrict__ bsum, int nb) {
    __shared__ int sm[256];
    int t = threadIdx.x;
    int v = (t < nb) ? bsum[t] : 0;
    sm[t] = v;
    __syncthreads();
    for (int off = 1; off < 256; off <<= 1) {
        int add = (t >= off) ? sm[t - off] : 0;
        __syncthreads();
        sm[t] += add;
        __syncthreads();
    }
    if (t < nb) bsum[t] = sm[t] - v;        // exclusive
}

__global__ void k_scanC(int* __restrict__ counts, const int* __restrict__ bsum, int N) {
    __shared__ int sm[256];
    int i = blockIdx.x * 256 + threadIdx.x, t = threadIdx.x;
    int v = (i < N) ? counts[i] : 0;
    sm[t] = v;
    __syncthreads();
    for (int off = 1; off < 256; off <<= 1) {
        int add = (t >= off) ? sm[t - off] : 0;
        __syncthreads();
        sm[t] += add;
        __syncthreads();
    }
    if (i < N) counts[i] = bsum[blockIdx.x] + sm[t] - v;   // exclusive prefix
}

// ---------------- K4: CSR fill (offs doubles as cursor; ends up = end offsets)
__global__ void k_fill(const int* __restrict__ src, const int* __restrict__ dst,
                       int* __restrict__ offs, int* __restrict__ csr_src, int E) {
    int i = blockIdx.x * blockDim.x + threadIdx.x;
    if (i >= E) return;
    int d = dst[i];
    int pos = atomicAdd(offs + d, 1);
    csr_src[pos] = src[i];
}

// ---------------- K5: per-node softmax + gather-aggregate (no atomics) ------
// One wave per dst node. ends[i] = end offset of node i (start = ends[i-1]).
__global__ __launch_bounds__(256) void k5_node(
        const int* __restrict__ csr_src, const int* __restrict__ ends,
        const float* __restrict__ el, const float* __restrict__ er,
        const float* __restrict__ z, float* __restrict__ out, int N) {
    const int lane = threadIdx.x & 63;
    const int node = blockIdx.x * 4 + (threadIdx.x >> 6);
    if (node >= N) return;

    const int start = (node == 0) ? 0 : ends[node - 1];
    const int end   = ends[node];
    float acc = 0.0f;

    if (end > start) {
        const float er_i = er[node];
        float e0 = 0.0f, e1 = 0.0f;
        int   s0 = 0,    s1 = 0;
        float m = -3.4e38f;

        // pass 1: gather logits, cache first two rounds in regs, running max
        int t = 0;
        for (int j = start + lane; j < end; j += 64, ++t) {
            int s = csr_src[j];
            float x = el[s] + er_i;
            float e = fmaxf(x, NEG_SLOPE * x);     // leaky_relu (slope<1)
            if (t == 0) { e0 = e; s0 = s; }
            else if (t == 1) { e1 = e; s1 = s; }
            m = fmaxf(m, e);
        }
        #pragma unroll
        for (int msk = 32; msk; msk >>= 1) m = fmaxf(m, __shfl_xor(m, msk, 64));

        // pass 2: sum of exp (reuse cached logits; overwrite caches with exp)
        float sum = 0.0f;
        t = 0;
        for (int j = start + lane; j < end; j += 64, ++t) {
            float e;
            if (t == 0) e = e0;
            else if (t == 1) e = e1;
            else {
                int s = csr_src[j];
                float x = el[s] + er_i;
                e = fmaxf(x, NEG_SLOPE * x);
            }
            float ex = __expf(e - m);
            if (t == 0) e0 = ex; else if (t == 1) e1 = ex;
            sum += ex;
        }
        #pragma unroll
        for (int msk = 32; msk; msk >>= 1) sum += __shfl_xor(sum, msk, 64);
        const float inv = 1.0f / sum;

        // pass 3: weighted gather of z rows (whole wave per edge)
        const int deg = end - start;
        for (int r = 0; r < deg; ++r) {
            int tt = r >> 6, owner = r & 63;
            int s; float ex;
            if (tt == 0)      { s = __shfl(s0, owner, 64); ex = __shfl(e0, owner, 64); }
            else if (tt == 1) { s = __shfl(s1, owner, 64); ex = __shfl(e1, owner, 64); }
            else {
                s = csr_src[start + r];
                float x = el[s] + er_i;
                float e = fmaxf(x, NEG_SLOPE * x);
                ex = __expf(e - m);
            }
            acc += (ex * inv) * z[(size_t)s * OUT_DIM + lane];
        }
    }
    out[(size_t)node * OUT_DIM + lane] = acc;
}

extern "C" void kernel_launch(void* const* d_in, const int* in_sizes, int n_in,
                              void* d_out, int out_size, void* d_ws, size_t ws_size,
                              hipStream_t stream) {
    const float* h   = (const float*)d_in[0];
    const float* W   = (const float*)d_in[1];
    const float* a   = (const float*)d_in[2];
    const int*   src = (const int*)d_in[3];
    const int*   dst = (const int*)d_in[4];
    float* out = (float*)d_out;

    const int N = in_sizes[0] / IN_DIM;     // 50000
    const int E = in_sizes[3];              // 800000

    // workspace layout (16.6 MB total; proven ws >= 16.8 MB from R0)
    float* z    = (float*)d_ws;             // N*64 floats
    float* el   = z + (size_t)N * OUT_DIM;  // N
    float* er   = el + N;                   // N
    int*   offs = (int*)(er + N);           // N   (counts -> excl scan -> cursor -> ends)
    int*   bsum = offs + N;                 // 256
    int*   csr_src = bsum + 256;            // E

    const int nb = (N + 255) / 256;         // 196 scan blocks

    k_zero<<<nb, 256, 0, stream>>>(offs, N);
    {
        int groups = (N + 7) / 8;
        k1_proj<<<(groups + 3) / 4, 256, 0, stream>>>(h, W, a, z, el, er, N);
    }
    k_hist<<<(E + 255) / 256, 256, 0, stream>>>(dst, offs, E);
    k_scanA<<<nb, 256, 0, stream>>>(offs, bsum, N);
    k_scanB<<<1, 256, 0, stream>>>(bsum, nb);
    k_scanC<<<nb, 256, 0, stream>>>(offs, bsum, N);
    k_fill<<<(E + 255) / 256, 256, 0, stream>>>(src, dst, offs, csr_src, E);
    k5_node<<<(N + 3) / 4, 256, 0, stream>>>(csr_src, offs, el, er, z, out, N);
}

// Round 3
// 272.812 us; speedup vs baseline: 1.5597x; 1.1516x over previous
//
#include <hip/hip_runtime.h>

#define IN_DIM 256
#define OUT_DIM 64
#define NEG_SLOPE 0.01f

// ---------------- K0: zero the histogram ----------------
__global__ void k_zero(int* __restrict__ counts, int N) {
    int i = blockIdx.x * blockDim.x + threadIdx.x;
    if (i < N) counts[i] = 0;
}

// ---------------- K1 v2: z = h @ W^T (+ fused el, er), W staged in LDS -----
// W transposed into LDS as wlds[k4][o] (float4 over k). Inner-loop read
// wlds[k4][lane] is lanes-contiguous ds_read_b128 -> conflict-free.
// One wave per 8-row group, grid-stride over groups. h-row loads are
// wave-uniform -> scalar cache.
__global__ __launch_bounds__(256, 2) void k1_proj(
        const float* __restrict__ h, const float* __restrict__ W,
        const float* __restrict__ a,
        float* __restrict__ z, float* __restrict__ el, float* __restrict__ er,
        int N, int nwaves_total) {
    __shared__ float4 wlds[64][64];           // [k4][o] = W[o][4k4..4k4+3], 64 KB

    // stage W: coalesced global read, transposed LDS write (one-time cost)
    for (int f = threadIdx.x; f < 64 * 64; f += 256) {
        int o = f >> 6, k4 = f & 63;
        wlds[k4][o] = ((const float4*)W)[f];  // f = o*64 + k4
    }
    __syncthreads();

    const int lane = threadIdx.x & 63;
    const int gwid = blockIdx.x * 4 + (threadIdx.x >> 6);
    const int ngroups = N >> 3;               // N % 8 == 0 (50000 = 8*6250)

    const float al = a[lane];
    const float ar = a[OUT_DIM + lane];

    for (int g = gwid; g < ngroups; g += nwaves_total) {
        const int r0 = g * 8;
        const float* __restrict__ hbase = h + (size_t)r0 * IN_DIM;

        float acc[8];
        #pragma unroll
        for (int r = 0; r < 8; ++r) acc[r] = 0.0f;

        for (int k4 = 0; k4 < 64; ++k4) {
            float4 w4 = wlds[k4][lane];
            #pragma unroll
            for (int r = 0; r < 8; ++r) {
                float4 h4 = *(const float4*)(hbase + r * IN_DIM + k4 * 4); // uniform
                acc[r] += h4.x * w4.x + h4.y * w4.y + h4.z * w4.z + h4.w * w4.w;
            }
        }

        #pragma unroll
        for (int r = 0; r < 8; ++r) {
            int row = r0 + r;
            z[(size_t)row * OUT_DIM + lane] = acc[r];
            float vl = acc[r] * al;
            float vr = acc[r] * ar;
            #pragma unroll
            for (int m = 32; m >= 1; m >>= 1) {
                vl += __shfl_xor(vl, m, 64);
                vr += __shfl_xor(vr, m, 64);
            }
            if (lane == 0) { el[row] = vl; er[row] = vr; }
        }
    }
}

// ---------------- K2: histogram of dst ----------------
__global__ void k_hist(const int* __restrict__ dst, int* __restrict__ counts, int E) {
    int i = blockIdx.x * blockDim.x + threadIdx.x;
    if (i < E) atomicAdd(counts + dst[i], 1);
}

// ---------------- K3: 3-phase exclusive scan over counts (in place) --------
__global__ void k_scanA(const int* __restrict__ counts, int* __restrict__ bsum, int N) {
    __shared__ int sm[256];
    int i = blockIdx.x * 256 + threadIdx.x;
    sm[threadIdx.x] = (i < N) ? counts[i] : 0;
    __syncthreads();
    for (int off = 128; off; off >>= 1) {
        if (threadIdx.x < off) sm[threadIdx.x] += sm[threadIdx.x + off];
        __syncthreads();
    }
    if (threadIdx.x == 0) bsum[blockIdx.x] = sm[0];
}

__global__ void k_scanB(int* __restrict__ bsum, int nb) {
    __shared__ int sm[256];
    int t = threadIdx.x;
    int v = (t < nb) ? bsum[t] : 0;
    sm[t] = v;
    __syncthreads();
    for (int off = 1; off < 256; off <<= 1) {
        int add = (t >= off) ? sm[t - off] : 0;
        __syncthreads();
        sm[t] += add;
        __syncthreads();
    }
    if (t < nb) bsum[t] = sm[t] - v;        // exclusive
}

__global__ void k_scanC(int* __restrict__ counts, const int* __restrict__ bsum, int N) {
    __shared__ int sm[256];
    int i = blockIdx.x * 256 + threadIdx.x, t = threadIdx.x;
    int v = (i < N) ? counts[i] : 0;
    sm[t] = v;
    __syncthreads();
    for (int off = 1; off < 256; off <<= 1) {
        int add = (t >= off) ? sm[t - off] : 0;
        __syncthreads();
        sm[t] += add;
        __syncthreads();
    }
    if (i < N) counts[i] = bsum[blockIdx.x] + sm[t] - v;   // exclusive prefix
}

// ---------------- K4: CSR fill (offs doubles as cursor; ends up = end offsets)
__global__ void k_fill(const int* __restrict__ src, const int* __restrict__ dst,
                       int* __restrict__ offs, int* __restrict__ csr_src, int E) {
    int i = blockIdx.x * blockDim.x + threadIdx.x;
    if (i >= E) return;
    int d = dst[i];
    int pos = atomicAdd(offs + d, 1);
    csr_src[pos] = src[i];
}

// ---------------- K5: per-node softmax + gather-aggregate (no atomics) ------
// One wave per dst node. ends[i] = end offset of node i (start = ends[i-1]).
__global__ __launch_bounds__(256) void k5_node(
        const int* __restrict__ csr_src, const int* __restrict__ ends,
        const float* __restrict__ el, const float* __restrict__ er,
        const float* __restrict__ z, float* __restrict__ out, int N) {
    const int lane = threadIdx.x & 63;
    const int node = blockIdx.x * 4 + (threadIdx.x >> 6);
    if (node >= N) return;

    const int start = (node == 0) ? 0 : ends[node - 1];
    const int end   = ends[node];
    float acc = 0.0f;

    if (end > start) {
        const float er_i = er[node];
        float e0 = 0.0f, e1 = 0.0f;
        int   s0 = 0,    s1 = 0;
        float m = -3.4e38f;

        // pass 1: gather logits, cache first two rounds in regs, running max
        int t = 0;
        for (int j = start + lane; j < end; j += 64, ++t) {
            int s = csr_src[j];
            float x = el[s] + er_i;
            float e = fmaxf(x, NEG_SLOPE * x);     // leaky_relu (slope<1)
            if (t == 0) { e0 = e; s0 = s; }
            else if (t == 1) { e1 = e; s1 = s; }
            m = fmaxf(m, e);
        }
        #pragma unroll
        for (int msk = 32; msk; msk >>= 1) m = fmaxf(m, __shfl_xor(m, msk, 64));

        // pass 2: sum of exp (reuse cached logits; overwrite caches with exp)
        float sum = 0.0f;
        t = 0;
        for (int j = start + lane; j < end; j += 64, ++t) {
            float e;
            if (t == 0) e = e0;
            else if (t == 1) e = e1;
            else {
                int s = csr_src[j];
                float x = el[s] + er_i;
                e = fmaxf(x, NEG_SLOPE * x);
            }
            float ex = __expf(e - m);
            if (t == 0) e0 = ex; else if (t == 1) e1 = ex;
            sum += ex;
        }
        #pragma unroll
        for (int msk = 32; msk; msk >>= 1) sum += __shfl_xor(sum, msk, 64);
        const float inv = 1.0f / sum;

        // pass 3: weighted gather of z rows (whole wave per edge)
        const int deg = end - start;
        for (int r = 0; r < deg; ++r) {
            int tt = r >> 6, owner = r & 63;
            int s; float ex;
            if (tt == 0)      { s = __shfl(s0, owner, 64); ex = __shfl(e0, owner, 64); }
            else if (tt == 1) { s = __shfl(s1, owner, 64); ex = __shfl(e1, owner, 64); }
            else {
                s = csr_src[start + r];
                float x = el[s] + er_i;
                float e = fmaxf(x, NEG_SLOPE * x);
                ex = __expf(e - m);
            }
            acc += (ex * inv) * z[(size_t)s * OUT_DIM + lane];
        }
    }
    out[(size_t)node * OUT_DIM + lane] = acc;
}

extern "C" void kernel_launch(void* const* d_in, const int* in_sizes, int n_in,
                              void* d_out, int out_size, void* d_ws, size_t ws_size,
                              hipStream_t stream) {
    const float* h   = (const float*)d_in[0];
    const float* W   = (const float*)d_in[1];
    const float* a   = (const float*)d_in[2];
    const int*   src = (const int*)d_in[3];
    const int*   dst = (const int*)d_in[4];
    float* out = (float*)d_out;

    const int N = in_sizes[0] / IN_DIM;     // 50000
    const int E = in_sizes[3];              // 800000

    // workspace layout
    float* z    = (float*)d_ws;             // N*64 floats
    float* el   = z + (size_t)N * OUT_DIM;  // N
    float* er   = el + N;                   // N
    int*   offs = (int*)(er + N);           // N   (counts -> excl scan -> cursor -> ends)
    int*   bsum = offs + N;                 // 256
    int*   csr_src = bsum + 256;            // E

    const int nb = (N + 255) / 256;         // 196 scan blocks

    k_zero<<<nb, 256, 0, stream>>>(offs, N);
    {
        const int nblocks = 512;            // 2 blocks/CU (64 KB LDS each)
        k1_proj<<<nblocks, 256, 0, stream>>>(h, W, a, z, el, er, N, nblocks * 4);
    }
    k_hist<<<(E + 255) / 256, 256, 0, stream>>>(dst, offs, E);
    k_scanA<<<nb, 256, 0, stream>>>(offs, bsum, N);
    k_scanB<<<1, 256, 0, stream>>>(bsum, nb);
    k_scanC<<<nb, 256, 0, stream>>>(offs, bsum, N);
    k_fill<<<(E + 255) / 256, 256, 0, stream>>>(src, dst, offs, csr_src, E);
    k5_node<<<(N + 3) / 4, 256, 0, stream>>>(csr_src, offs, el, er, z, out, N);
}

// Round 4
// 190.589 us; speedup vs baseline: 2.2326x; 1.4314x over previous
//
#include <hip/hip_runtime.h>

#define IN_DIM 256
#define OUT_DIM 64
#define NEG_SLOPE 0.01f

typedef __attribute__((ext_vector_type(8))) short short8v;   // 8 bf16 (4 VGPRs)
typedef __attribute__((ext_vector_type(4))) float float4v;   // MFMA C/D

// fp32 -> bf16 round-to-nearest-even
__device__ __forceinline__ unsigned short f2bf(float f) {
    unsigned u = __float_as_uint(f);
    return (unsigned short)((u + 0x7FFFu + ((u >> 16) & 1u)) >> 16);
}

// ---------------- K0: zero the histogram ----------------
__global__ void k_zero(int* __restrict__ counts, int N) {
    int i = blockIdx.x * blockDim.x + threadIdx.x;
    if (i < N) counts[i] = 0;
}

// ---------------- Kw: convert W to bf16 (32 KB -> L1-resident) -------------
__global__ void k_wcvt(const float* __restrict__ W, unsigned short* __restrict__ Wb, int n) {
    int i = blockIdx.x * blockDim.x + threadIdx.x;
    if (i < n) Wb[i] = f2bf(W[i]);
}

// ---------------- K1 v3: z = h @ W^T via MFMA bf16 (+ fused el, er) --------
// One wave per 16-row tile; 4 x mfma_f32_16x16x32_bf16 accumulators cover
// 16 rows x 64 cols. A-frag: lane reads h[r0+(l&15)][k0..k0+7] (fp32->bf16).
// B-frag: lane reads Wb[n*16+(l&15)][k0..k0+7] (dwordx4, L1-hot).
// C/D layout (HW-verified): col = lane&15, row = (lane>>4)*4 + reg.
__global__ __launch_bounds__(256) void k1_mfma(
        const float* __restrict__ h, const unsigned short* __restrict__ Wb,
        const float* __restrict__ a,
        float* __restrict__ z, float* __restrict__ el, float* __restrict__ er,
        int M) {
    const int lane = threadIdx.x & 63;
    const int wid  = (blockIdx.x * 256 + threadIdx.x) >> 6;  // global wave id
    const int r0 = wid * 16;
    if (r0 >= M) return;

    const int lrow = lane & 15;       // A-row / C-col selector
    const int kgrp = lane >> 4;       // 0..3
    const int k0   = kgrp * 8;

    float4v acc[4];
    #pragma unroll
    for (int n = 0; n < 4; ++n) acc[n] = (float4v){0.f, 0.f, 0.f, 0.f};

    const float* __restrict__ hrow = h + (size_t)(r0 + lrow) * IN_DIM;

    #pragma unroll
    for (int step = 0; step < 8; ++step) {
        const int kk = step * 32 + k0;
        float4 ha = *(const float4*)(hrow + kk);
        float4 hb = *(const float4*)(hrow + kk + 4);
        short8v afrag;
        afrag[0] = (short)f2bf(ha.x); afrag[1] = (short)f2bf(ha.y);
        afrag[2] = (short)f2bf(ha.z); afrag[3] = (short)f2bf(ha.w);
        afrag[4] = (short)f2bf(hb.x); afrag[5] = (short)f2bf(hb.y);
        afrag[6] = (short)f2bf(hb.z); afrag[7] = (short)f2bf(hb.w);
        #pragma unroll
        for (int n = 0; n < 4; ++n) {
            short8v bfrag = *(const short8v*)(Wb + (size_t)(n * 16 + lrow) * IN_DIM + kk);
            acc[n] = __builtin_amdgcn_mfma_f32_16x16x32_bf16(afrag, bfrag, acc[n], 0, 0, 0);
        }
    }

    // epilogue: write z, fused el/er (a_l = a[0:64], a_r = a[64:128])
    float al4[4], ar4[4];
    #pragma unroll
    for (int n = 0; n < 4; ++n) {
        al4[n] = a[n * 16 + lrow];
        ar4[n] = a[OUT_DIM + n * 16 + lrow];
    }
    #pragma unroll
    for (int j = 0; j < 4; ++j) {
        const int row = r0 + kgrp * 4 + j;
        float vl = 0.f, vr = 0.f;
        #pragma unroll
        for (int n = 0; n < 4; ++n) {
            float v = acc[n][j];
            z[(size_t)row * OUT_DIM + n * 16 + lrow] = v;
            vl += v * al4[n];
            vr += v * ar4[n];
        }
        #pragma unroll
        for (int m = 8; m >= 1; m >>= 1) {
            vl += __shfl_xor(vl, m, 64);
            vr += __shfl_xor(vr, m, 64);
        }
        if (lrow == 0) { el[row] = vl; er[row] = vr; }
    }
}

// ---------------- K2: histogram of dst ----------------
__global__ void k_hist(const int* __restrict__ dst, int* __restrict__ counts, int E) {
    int i = blockIdx.x * blockDim.x + threadIdx.x;
    if (i < E) atomicAdd(counts + dst[i], 1);
}

// ---------------- K3: 3-phase exclusive scan over counts (in place) --------
__global__ void k_scanA(const int* __restrict__ counts, int* __restrict__ bsum, int N) {
    __shared__ int sm[256];
    int i = blockIdx.x * 256 + threadIdx.x;
    sm[threadIdx.x] = (i < N) ? counts[i] : 0;
    __syncthreads();
    for (int off = 128; off; off >>= 1) {
        if (threadIdx.x < off) sm[threadIdx.x] += sm[threadIdx.x + off];
        __syncthreads();
    }
    if (threadIdx.x == 0) bsum[blockIdx.x] = sm[0];
}

__global__ void k_scanB(int* __restrict__ bsum, int nb) {
    __shared__ int sm[256];
    int t = threadIdx.x;
    int v = (t < nb) ? bsum[t] : 0;
    sm[t] = v;
    __syncthreads();
    for (int off = 1; off < 256; off <<= 1) {
        int add = (t >= off) ? sm[t - off] : 0;
        __syncthreads();
        sm[t] += add;
        __syncthreads();
    }
    if (t < nb) bsum[t] = sm[t] - v;        // exclusive
}

__global__ void k_scanC(int* __restrict__ counts, const int* __restrict__ bsum, int N) {
    __shared__ int sm[256];
    int i = blockIdx.x * 256 + threadIdx.x, t = threadIdx.x;
    int v = (i < N) ? counts[i] : 0;
    sm[t] = v;
    __syncthreads();
    for (int off = 1; off < 256; off <<= 1) {
        int add = (t >= off) ? sm[t - off] : 0;
        __syncthreads();
        sm[t] += add;
        __syncthreads();
    }
    if (i < N) counts[i] = bsum[blockIdx.x] + sm[t] - v;   // exclusive prefix
}

// ---------------- K4: CSR fill (offs doubles as cursor; ends up = end offsets)
__global__ void k_fill(const int* __restrict__ src, const int* __restrict__ dst,
                       int* __restrict__ offs, int* __restrict__ csr_src, int E) {
    int i = blockIdx.x * blockDim.x + threadIdx.x;
    if (i >= E) return;
    int d = dst[i];
    int pos = atomicAdd(offs + d, 1);
    csr_src[pos] = src[i];
}

// ---------------- K5: per-node softmax + gather-aggregate (no atomics) ------
// One wave per dst node. ends[i] = end offset of node i (start = ends[i-1]).
__global__ __launch_bounds__(256) void k5_node(
        const int* __restrict__ csr_src, const int* __restrict__ ends,
        const float* __restrict__ el, const float* __restrict__ er,
        const float* __restrict__ z, float* __restrict__ out, int N) {
    const int lane = threadIdx.x & 63;
    const int node = blockIdx.x * 4 + (threadIdx.x >> 6);
    if (node >= N) return;

    const int start = (node == 0) ? 0 : ends[node - 1];
    const int end   = ends[node];
    float acc = 0.0f;

    if (end > start) {
        const float er_i = er[node];
        float e0 = 0.0f, e1 = 0.0f;
        int   s0 = 0,    s1 = 0;
        float m = -3.4e38f;

        // pass 1: gather logits, cache first two rounds in regs, running max
        int t = 0;
        for (int j = start + lane; j < end; j += 64, ++t) {
            int s = csr_src[j];
            float x = el[s] + er_i;
            float e = fmaxf(x, NEG_SLOPE * x);     // leaky_relu (slope<1)
            if (t == 0) { e0 = e; s0 = s; }
            else if (t == 1) { e1 = e; s1 = s; }
            m = fmaxf(m, e);
        }
        #pragma unroll
        for (int msk = 32; msk; msk >>= 1) m = fmaxf(m, __shfl_xor(m, msk, 64));

        // pass 2: sum of exp (reuse cached logits; overwrite caches with exp)
        float sum = 0.0f;
        t = 0;
        for (int j = start + lane; j < end; j += 64, ++t) {
            float e;
            if (t == 0) e = e0;
            else if (t == 1) e = e1;
            else {
                int s = csr_src[j];
                float x = el[s] + er_i;
                e = fmaxf(x, NEG_SLOPE * x);
            }
            float ex = __expf(e - m);
            if (t == 0) e0 = ex; else if (t == 1) e1 = ex;
            sum += ex;
        }
        #pragma unroll
        for (int msk = 32; msk; msk >>= 1) sum += __shfl_xor(sum, msk, 64);
        const float inv = 1.0f / sum;

        // pass 3: weighted gather of z rows (whole wave per edge)
        const int deg = end - start;
        for (int r = 0; r < deg; ++r) {
            int tt = r >> 6, owner = r & 63;
            int s; float ex;
            if (tt == 0)      { s = __shfl(s0, owner, 64); ex = __shfl(e0, owner, 64); }
            else if (tt == 1) { s = __shfl(s1, owner, 64); ex = __shfl(e1, owner, 64); }
            else {
                s = csr_src[start + r];
                float x = el[s] + er_i;
                float e = fmaxf(x, NEG_SLOPE * x);
                ex = __expf(e - m);
            }
            acc += (ex * inv) * z[(size_t)s * OUT_DIM + lane];
        }
    }
    out[(size_t)node * OUT_DIM + lane] = acc;
}

extern "C" void kernel_launch(void* const* d_in, const int* in_sizes, int n_in,
                              void* d_out, int out_size, void* d_ws, size_t ws_size,
                              hipStream_t stream) {
    const float* h   = (const float*)d_in[0];
    const float* W   = (const float*)d_in[1];
    const float* a   = (const float*)d_in[2];
    const int*   src = (const int*)d_in[3];
    const int*   dst = (const int*)d_in[4];
    float* out = (float*)d_out;

    const int N = in_sizes[0] / IN_DIM;     // 50000
    const int E = in_sizes[3];              // 800000

    // workspace layout (~16.65 MB; ws proven >= 16.8 MB by R0)
    float* z    = (float*)d_ws;             // N*64 floats
    float* el   = z + (size_t)N * OUT_DIM;  // N
    float* er   = el + N;                   // N
    int*   offs = (int*)(er + N);           // N   (counts -> excl scan -> cursor -> ends)
    int*   bsum = offs + N;                 // 256
    int*   csr_src = bsum + 256;            // E
    unsigned short* Wb = (unsigned short*)(csr_src + E);  // 64*256 bf16 (32 KB)

    const int nb = (N + 255) / 256;         // 196 scan blocks

    k_zero<<<nb, 256, 0, stream>>>(offs, N);
    k_wcvt<<<(OUT_DIM * IN_DIM + 255) / 256, 256, 0, stream>>>(W, Wb, OUT_DIM * IN_DIM);
    {
        const int waves = (N + 15) / 16;    // 3125 row-tiles
        k1_mfma<<<(waves + 3) / 4, 256, 0, stream>>>(h, Wb, a, z, el, er, N);
    }
    k_hist<<<(E + 255) / 256, 256, 0, stream>>>(dst, offs, E);
    k_scanA<<<nb, 256, 0, stream>>>(offs, bsum, N);
    k_scanB<<<1, 256, 0, stream>>>(bsum, nb);
    k_scanC<<<nb, 256, 0, stream>>>(offs, bsum, N);
    k_fill<<<(E + 255) / 256, 256, 0, stream>>>(src, dst, offs, csr_src, E);
    k5_node<<<(N + 3) / 4, 256, 0, stream>>>(csr_src, offs, el, er, z, out, N);
}

// Round 5
// 164.369 us; speedup vs baseline: 2.5888x; 1.1595x over previous
//
#include <hip/hip_runtime.h>

#define IN_DIM 256
#define OUT_DIM 64
#define NEG_SLOPE 0.01f

typedef __attribute__((ext_vector_type(8))) short short8v;   // 8 bf16 (4 VGPRs)
typedef __attribute__((ext_vector_type(4))) float float4v;   // MFMA C/D

// fp32 -> bf16 round-to-nearest-even
__device__ __forceinline__ unsigned short f2bf(float f) {
    unsigned u = __float_as_uint(f);
    return (unsigned short)((u + 0x7FFFu + ((u >> 16) & 1u)) >> 16);
}
__device__ __forceinline__ float bf2f(unsigned short u) {
    return __uint_as_float((unsigned)u << 16);
}

// ---------------- K0: zero histogram + convert W to bf16 (fused) -----------
__global__ void k_init(const float* __restrict__ W, unsigned short* __restrict__ Wb,
                       int* __restrict__ counts, int N) {
    int i = blockIdx.x * blockDim.x + threadIdx.x;
    if (i < N) counts[i] = 0;
    if (i < OUT_DIM * IN_DIM) Wb[i] = f2bf(W[i]);
}

// ---------------- K1: z = h @ W^T via MFMA bf16 (+ fused el, er) -----------
// One wave per 16-row tile; 4 x mfma_f32_16x16x32_bf16 accumulators cover
// 16 rows x 64 cols. z written as bf16 (only k5 reads it).
// C/D layout (HW-verified): col = lane&15, row = (lane>>4)*4 + reg.
__global__ __launch_bounds__(256) void k1_mfma(
        const float* __restrict__ h, const unsigned short* __restrict__ Wb,
        const float* __restrict__ a,
        unsigned short* __restrict__ zb, float* __restrict__ el, float* __restrict__ er,
        int M) {
    const int lane = threadIdx.x & 63;
    const int wid  = (blockIdx.x * 256 + threadIdx.x) >> 6;  // global wave id
    const int r0 = wid * 16;
    if (r0 >= M) return;

    const int lrow = lane & 15;       // A-row / C-col selector
    const int kgrp = lane >> 4;       // 0..3
    const int k0   = kgrp * 8;

    float4v acc[4];
    #pragma unroll
    for (int n = 0; n < 4; ++n) acc[n] = (float4v){0.f, 0.f, 0.f, 0.f};

    const float* __restrict__ hrow = h + (size_t)(r0 + lrow) * IN_DIM;

    #pragma unroll
    for (int step = 0; step < 8; ++step) {
        const int kk = step * 32 + k0;
        float4 ha = *(const float4*)(hrow + kk);
        float4 hb = *(const float4*)(hrow + kk + 4);
        short8v afrag;
        afrag[0] = (short)f2bf(ha.x); afrag[1] = (short)f2bf(ha.y);
        afrag[2] = (short)f2bf(ha.z); afrag[3] = (short)f2bf(ha.w);
        afrag[4] = (short)f2bf(hb.x); afrag[5] = (short)f2bf(hb.y);
        afrag[6] = (short)f2bf(hb.z); afrag[7] = (short)f2bf(hb.w);
        #pragma unroll
        for (int n = 0; n < 4; ++n) {
            short8v bfrag = *(const short8v*)(Wb + (size_t)(n * 16 + lrow) * IN_DIM + kk);
            acc[n] = __builtin_amdgcn_mfma_f32_16x16x32_bf16(afrag, bfrag, acc[n], 0, 0, 0);
        }
    }

    // epilogue: write zb (bf16), fused el/er from fp32 accumulators
    float al4[4], ar4[4];
    #pragma unroll
    for (int n = 0; n < 4; ++n) {
        al4[n] = a[n * 16 + lrow];
        ar4[n] = a[OUT_DIM + n * 16 + lrow];
    }
    #pragma unroll
    for (int j = 0; j < 4; ++j) {
        const int row = r0 + kgrp * 4 + j;
        float vl = 0.f, vr = 0.f;
        #pragma unroll
        for (int n = 0; n < 4; ++n) {
            float v = acc[n][j];
            zb[(size_t)row * OUT_DIM + n * 16 + lrow] = f2bf(v);
            vl += v * al4[n];
            vr += v * ar4[n];
        }
        #pragma unroll
        for (int m = 8; m >= 1; m >>= 1) {
            vl += __shfl_xor(vl, m, 64);
            vr += __shfl_xor(vr, m, 64);
        }
        if (lrow == 0) { el[row] = vl; er[row] = vr; }
    }
}

// ---------------- K2: histogram of dst ----------------
__global__ void k_hist(const int* __restrict__ dst, int* __restrict__ counts, int E) {
    int i = blockIdx.x * blockDim.x + threadIdx.x;
    if (i < E) atomicAdd(counts + dst[i], 1);
}

// ---------------- K3: 3-phase exclusive scan over counts (in place) --------
__global__ void k_scanA(const int* __restrict__ counts, int* __restrict__ bsum, int N) {
    __shared__ int sm[256];
    int i = blockIdx.x * 256 + threadIdx.x;
    sm[threadIdx.x] = (i < N) ? counts[i] : 0;
    __syncthreads();
    for (int off = 128; off; off >>= 1) {
        if (threadIdx.x < off) sm[threadIdx.x] += sm[threadIdx.x + off];
        __syncthreads();
    }
    if (threadIdx.x == 0) bsum[blockIdx.x] = sm[0];
}

__global__ void k_scanB(int* __restrict__ bsum, int nb) {
    __shared__ int sm[256];
    int t = threadIdx.x;
    int v = (t < nb) ? bsum[t] : 0;
    sm[t] = v;
    __syncthreads();
    for (int off = 1; off < 256; off <<= 1) {
        int add = (t >= off) ? sm[t - off] : 0;
        __syncthreads();
        sm[t] += add;
        __syncthreads();
    }
    if (t < nb) bsum[t] = sm[t] - v;        // exclusive
}

__global__ void k_scanC(int* __restrict__ counts, const int* __restrict__ bsum, int N) {
    __shared__ int sm[256];
    int i = blockIdx.x * 256 + threadIdx.x, t = threadIdx.x;
    int v = (i < N) ? counts[i] : 0;
    sm[t] = v;
    __syncthreads();
    for (int off = 1; off < 256; off <<= 1) {
        int add = (t >= off) ? sm[t - off] : 0;
        __syncthreads();
        sm[t] += add;
        __syncthreads();
    }
    if (i < N) counts[i] = bsum[blockIdx.x] + sm[t] - v;   // exclusive prefix
}

// ---------------- K4: CSR fill (offs doubles as cursor; ends up = end offsets)
__global__ void k_fill(const int* __restrict__ src, const int* __restrict__ dst,
                       int* __restrict__ offs, int* __restrict__ csr_src, int E) {
    int i = blockIdx.x * blockDim.x + threadIdx.x;
    if (i >= E) return;
    int d = dst[i];
    int pos = atomicAdd(offs + d, 1);
    csr_src[pos] = src[i];
}

// ---------------- K5: per-node softmax + gather-aggregate (no atomics) ------
// One wave per dst node. bf16 z rows (128 B/row), 4-way unrolled gather.
__global__ __launch_bounds__(256) void k5_node(
        const int* __restrict__ csr_src, const int* __restrict__ ends,
        const float* __restrict__ el, const float* __restrict__ er,
        const unsigned short* __restrict__ zb, float* __restrict__ out, int N) {
    const int lane = threadIdx.x & 63;
    const int node = blockIdx.x * 4 + (threadIdx.x >> 6);
    if (node >= N) return;

    const int start = (node == 0) ? 0 : ends[node - 1];
    const int end   = ends[node];
    const int deg   = end - start;
    float acc = 0.0f;

    if (deg > 0 && deg <= 64) {
        // ---- fast path: whole neighbor list cached in one register round ----
        const float er_i = er[node];
        int   s0 = 0;
        float m  = -3.4e38f;
        float e0 = 0.0f;
        if (lane < deg) {
            s0 = csr_src[start + lane];
            float x = el[s0] + er_i;
            e0 = fmaxf(x, NEG_SLOPE * x);
            m  = e0;
        }
        #pragma unroll
        for (int msk = 32; msk; msk >>= 1) m = fmaxf(m, __shfl_xor(m, msk, 64));
        float ex0 = (lane < deg) ? __expf(e0 - m) : 0.0f;
        float sum = ex0;
        #pragma unroll
        for (int msk = 32; msk; msk >>= 1) sum += __shfl_xor(sum, msk, 64);
        const float inv = 1.0f / sum;

        float a0 = 0.f, a1 = 0.f, a2 = 0.f, a3 = 0.f;
        int r = 0;
        for (; r + 4 <= deg; r += 4) {
            int   sa = __shfl(s0,  r,     64), sb = __shfl(s0,  r + 1, 64);
            int   sc = __shfl(s0,  r + 2, 64), sd = __shfl(s0,  r + 3, 64);
            float wa = __shfl(ex0, r,     64), wb = __shfl(ex0, r + 1, 64);
            float wc = __shfl(ex0, r + 2, 64), wd = __shfl(ex0, r + 3, 64);
            float za = bf2f(zb[(size_t)sa * OUT_DIM + lane]);
            float zbv = bf2f(zb[(size_t)sb * OUT_DIM + lane]);
            float zc = bf2f(zb[(size_t)sc * OUT_DIM + lane]);
            float zd = bf2f(zb[(size_t)sd * OUT_DIM + lane]);
            a0 += wa * za; a1 += wb * zbv; a2 += wc * zc; a3 += wd * zd;
        }
        for (; r < deg; ++r) {
            int   sa = __shfl(s0,  r, 64);
            float wa = __shfl(ex0, r, 64);
            a0 += wa * bf2f(zb[(size_t)sa * OUT_DIM + lane]);
        }
        acc = ((a0 + a1) + (a2 + a3)) * inv;
    } else if (deg > 64) {
        // ---- generic path (rare: avg deg = 16) ----
        const float er_i = er[node];
        float e0 = 0.0f, e1 = 0.0f;
        int   s0 = 0,    s1 = 0;
        float m = -3.4e38f;
        int t = 0;
        for (int j = start + lane; j < end; j += 64, ++t) {
            int s = csr_src[j];
            float x = el[s] + er_i;
            float e = fmaxf(x, NEG_SLOPE * x);
            if (t == 0) { e0 = e; s0 = s; }
            else if (t == 1) { e1 = e; s1 = s; }
            m = fmaxf(m, e);
        }
        #pragma unroll
        for (int msk = 32; msk; msk >>= 1) m = fmaxf(m, __shfl_xor(m, msk, 64));
        float sum = 0.0f;
        t = 0;
        for (int j = start + lane; j < end; j += 64, ++t) {
            float e;
            if (t == 0) e = e0;
            else if (t == 1) e = e1;
            else {
                int s = csr_src[j];
                float x = el[s] + er_i;
                e = fmaxf(x, NEG_SLOPE * x);
            }
            float ex = __expf(e - m);
            if (t == 0) e0 = ex; else if (t == 1) e1 = ex;
            sum += ex;
        }
        #pragma unroll
        for (int msk = 32; msk; msk >>= 1) sum += __shfl_xor(sum, msk, 64);
        const float inv = 1.0f / sum;

        for (int r = 0; r < deg; ++r) {
            int tt = r >> 6, owner = r & 63;
            int s; float ex;
            if (tt == 0)      { s = __shfl(s0, owner, 64); ex = __shfl(e0, owner, 64); }
            else if (tt == 1) { s = __shfl(s1, owner, 64); ex = __shfl(e1, owner, 64); }
            else {
                s = csr_src[start + r];
                float x = el[s] + er_i;
                float e = fmaxf(x, NEG_SLOPE * x);
                ex = __expf(e - m);
            }
            acc += ex * bf2f(zb[(size_t)s * OUT_DIM + lane]);
        }
        acc *= inv;
    }
    out[(size_t)node * OUT_DIM + lane] = acc;
}

extern "C" void kernel_launch(void* const* d_in, const int* in_sizes, int n_in,
                              void* d_out, int out_size, void* d_ws, size_t ws_size,
                              hipStream_t stream) {
    const float* h   = (const float*)d_in[0];
    const float* W   = (const float*)d_in[1];
    const float* a   = (const float*)d_in[2];
    const int*   src = (const int*)d_in[3];
    const int*   dst = (const int*)d_in[4];
    float* out = (float*)d_out;

    const int N = in_sizes[0] / IN_DIM;     // 50000
    const int E = in_sizes[3];              // 800000

    // workspace layout (~10.3 MB)
    unsigned short* zb = (unsigned short*)d_ws;        // N*64 bf16 (6.4 MB)
    float* el   = (float*)(zb + (size_t)N * OUT_DIM);  // N
    float* er   = el + N;                              // N
    int*   offs = (int*)(er + N);                      // N
    int*   bsum = offs + N;                            // 256
    int*   csr_src = bsum + 256;                       // E
    unsigned short* Wb = (unsigned short*)(csr_src + E); // 64*256 bf16 (32 KB)

    const int nb = (N + 255) / 256;         // 196 scan blocks

    k_init<<<nb, 256, 0, stream>>>(W, Wb, offs, N);
    {
        const int waves = (N + 15) / 16;    // 3125 row-tiles
        k1_mfma<<<(waves + 3) / 4, 256, 0, stream>>>(h, Wb, a, zb, el, er, N);
    }
    k_hist<<<(E + 255) / 256, 256, 0, stream>>>(dst, offs, E);
    k_scanA<<<nb, 256, 0, stream>>>(offs, bsum, N);
    k_scanB<<<1, 256, 0, stream>>>(bsum, nb);
    k_scanC<<<nb, 256, 0, stream>>>(offs, bsum, N);
    k_fill<<<(E + 255) / 256, 256, 0, stream>>>(src, dst, offs, csr_src, E);
    k5_node<<<(N + 3) / 4, 256, 0, stream>>>(csr_src, offs, el, er, zb, out, N);
}

// Round 6
// 107.617 us; speedup vs baseline: 3.9540x; 1.5273x over previous
//
#include <hip/hip_runtime.h>

#define IN_DIM 256
#define OUT_DIM 64
#define NEG_SLOPE 0.01f
#define CHUNK 4096   // edges per kA_scatter block

typedef __attribute__((ext_vector_type(8))) short short8v;   // 8 bf16 (4 VGPRs)
typedef __attribute__((ext_vector_type(4))) float float4v;   // MFMA C/D

// fp32 -> bf16 round-to-nearest-even
__device__ __forceinline__ unsigned short f2bf(float f) {
    unsigned u = __float_as_uint(f);
    return (unsigned short)((u + 0x7FFFu + ((u >> 16) & 1u)) >> 16);
}
__device__ __forceinline__ float bf2f(unsigned short u) {
    return __uint_as_float((unsigned)u << 16);
}

// ---------------- K0: zero bucket counters/cursors + convert W to bf16 -----
__global__ void k_init(const float* __restrict__ W, unsigned short* __restrict__ Wb,
                       int* __restrict__ bc, int* __restrict__ cursor, int nbuck) {
    int i = blockIdx.x * blockDim.x + threadIdx.x;
    if (i < OUT_DIM * IN_DIM) Wb[i] = f2bf(W[i]);
    if (i < nbuck) { bc[i] = 0; cursor[i] = 0; }
}

// ---------------- K1: z = h @ W^T via MFMA bf16 (+ fused el, er) -----------
// C/D layout (HW-verified): col = lane&15, row = (lane>>4)*4 + reg.
__global__ __launch_bounds__(256) void k1_mfma(
        const float* __restrict__ h, const unsigned short* __restrict__ Wb,
        const float* __restrict__ a,
        unsigned short* __restrict__ zb, float* __restrict__ el, float* __restrict__ er,
        int M) {
    const int lane = threadIdx.x & 63;
    const int wid  = (blockIdx.x * 256 + threadIdx.x) >> 6;
    const int r0 = wid * 16;
    if (r0 >= M) return;

    const int lrow = lane & 15;
    const int kgrp = lane >> 4;
    const int k0   = kgrp * 8;

    float4v acc[4];
    #pragma unroll
    for (int n = 0; n < 4; ++n) acc[n] = (float4v){0.f, 0.f, 0.f, 0.f};

    const float* __restrict__ hrow = h + (size_t)(r0 + lrow) * IN_DIM;

    #pragma unroll
    for (int step = 0; step < 8; ++step) {
        const int kk = step * 32 + k0;
        float4 ha = *(const float4*)(hrow + kk);
        float4 hb = *(const float4*)(hrow + kk + 4);
        short8v afrag;
        afrag[0] = (short)f2bf(ha.x); afrag[1] = (short)f2bf(ha.y);
        afrag[2] = (short)f2bf(ha.z); afrag[3] = (short)f2bf(ha.w);
        afrag[4] = (short)f2bf(hb.x); afrag[5] = (short)f2bf(hb.y);
        afrag[6] = (short)f2bf(hb.z); afrag[7] = (short)f2bf(hb.w);
        #pragma unroll
        for (int n = 0; n < 4; ++n) {
            short8v bfrag = *(const short8v*)(Wb + (size_t)(n * 16 + lrow) * IN_DIM + kk);
            acc[n] = __builtin_amdgcn_mfma_f32_16x16x32_bf16(afrag, bfrag, acc[n], 0, 0, 0);
        }
    }

    float al4[4], ar4[4];
    #pragma unroll
    for (int n = 0; n < 4; ++n) {
        al4[n] = a[n * 16 + lrow];
        ar4[n] = a[OUT_DIM + n * 16 + lrow];
    }
    #pragma unroll
    for (int j = 0; j < 4; ++j) {
        const int row = r0 + kgrp * 4 + j;
        float vl = 0.f, vr = 0.f;
        #pragma unroll
        for (int n = 0; n < 4; ++n) {
            float v = acc[n][j];
            zb[(size_t)row * OUT_DIM + n * 16 + lrow] = f2bf(v);
            vl += v * al4[n];
            vr += v * ar4[n];
        }
        #pragma unroll
        for (int m = 8; m >= 1; m >>= 1) {
            vl += __shfl_xor(vl, m, 64);
            vr += __shfl_xor(vr, m, 64);
        }
        if (lrow == 0) { el[row] = vl; er[row] = vr; }
    }
}

// ---------------- kA_count: bucket histogram (bucket = dst>>8, 196 buckets) -
__global__ void kA_count(const int* __restrict__ dst, int* __restrict__ bc,
                         int E, int nbuck) {
    __shared__ int hist[256];
    hist[threadIdx.x] = 0;
    __syncthreads();
    for (int i = blockIdx.x * blockDim.x + threadIdx.x; i < E;
         i += gridDim.x * blockDim.x)
        atomicAdd(&hist[dst[i] >> 8], 1);
    __syncthreads();
    if (threadIdx.x < nbuck && hist[threadIdx.x])
        atomicAdd(&bc[threadIdx.x], hist[threadIdx.x]);
}

// ---------------- kA_scan: one-block exclusive scan of bucket counts --------
__global__ void kA_scan(const int* __restrict__ bc, int* __restrict__ bstart, int nbuck) {
    __shared__ int sm[256];
    int t = threadIdx.x;
    int v = (t < nbuck) ? bc[t] : 0;
    sm[t] = v;
    __syncthreads();
    for (int off = 1; off < 256; off <<= 1) {
        int add = (t >= off) ? sm[t - off] : 0;
        __syncthreads();
        sm[t] += add;
        __syncthreads();
    }
    if (t < nbuck) bstart[t] = sm[t] - v;
    if (t == 0) bstart[nbuck] = sm[255];
}

// ---------------- kA_scatter: partition edges into buckets, coalesced -------
// Per-block: LDS hist -> scan -> rank -> stage packed (dst<<16|src) in bucket
// order -> reserve global runs (1 atomic/bucket) -> coalesced run writes.
// Requires src,dst < 65536 (N=50000 ok).
__global__ __launch_bounds__(256) void kA_scatter(
        const int* __restrict__ src, const int* __restrict__ dst,
        const int* __restrict__ bstart, int* __restrict__ cursor,
        unsigned* __restrict__ bucketbuf, int E, int nbuck) {
    __shared__ unsigned stag[CHUNK];
    __shared__ int cnt[256], lofs[256], lcur[256], tb[256];
    const int t = threadIdx.x;
    const int base = blockIdx.x * CHUNK;
    const int n = min(CHUNK, E - base);

    cnt[t] = 0;
    __syncthreads();

    int es[16], ed[16];
    #pragma unroll
    for (int k = 0; k < 16; ++k) {
        int p = t + k * 256;
        if (p < n) {
            es[k] = src[base + p];
            ed[k] = dst[base + p];
            atomicAdd(&cnt[ed[k] >> 8], 1);
        }
    }
    __syncthreads();

    // exclusive scan of cnt -> lofs
    lofs[t] = cnt[t];
    __syncthreads();
    for (int off = 1; off < 256; off <<= 1) {
        int add = (t >= off) ? lofs[t - off] : 0;
        __syncthreads();
        lofs[t] += add;
        __syncthreads();
    }
    lofs[t] -= cnt[t];
    __syncthreads();

    // reserve global runs; translate base for staging position -> global
    if (t < nbuck) {
        int c = cnt[t];
        int g = c ? atomicAdd(&cursor[t], c) : 0;
        tb[t] = bstart[t] + g - lofs[t];
    }
    lcur[t] = lofs[t];
    __syncthreads();

    // rank + stage in bucket-sorted order
    #pragma unroll
    for (int k = 0; k < 16; ++k) {
        int p = t + k * 256;
        if (p < n) {
            int b = ed[k] >> 8;
            int pos = atomicAdd(&lcur[b], 1);
            stag[pos] = ((unsigned)ed[k] << 16) | (unsigned)es[k];
        }
    }
    __syncthreads();

    // coalesced run writes (consecutive p -> same bucket run)
    #pragma unroll
    for (int k = 0; k < 16; ++k) {
        int p = t + k * 256;
        if (p < n) {
            unsigned v = stag[p];
            int b = v >> 24;                 // = dst>>8
            bucketbuf[tb[b] + p] = v;
        }
    }
}

// ---------------- kB_build: per-bucket local CSR + ends --------------------
// One block per bucket (256 local nodes). Scatter window ~16 KB, block-local.
__global__ __launch_bounds__(256) void kB_build(
        const unsigned* __restrict__ bucketbuf, const int* __restrict__ bc,
        const int* __restrict__ bstart,
        int* __restrict__ csr_src, int* __restrict__ ends, int N) {
    __shared__ int lcnt[256], lofs[256], lcur[256];
    const int b = blockIdx.x, t = threadIdx.x;
    const int start = bstart[b];
    const int cnt = bc[b];
    const int node0 = b << 8;
    const int nloc = min(256, N - node0);

    lcnt[t] = 0;
    __syncthreads();
    for (int i = t; i < cnt; i += 256)
        atomicAdd(&lcnt[(bucketbuf[start + i] >> 16) & 255], 1);
    __syncthreads();

    // inclusive scan -> lofs
    lofs[t] = lcnt[t];
    __syncthreads();
    for (int off = 1; off < 256; off <<= 1) {
        int add = (t >= off) ? lofs[t - off] : 0;
        __syncthreads();
        lofs[t] += add;
        __syncthreads();
    }
    if (t < nloc) ends[node0 + t] = start + lofs[t];   // global inclusive end
    lcur[t] = lofs[t] - lcnt[t];                        // local exclusive start
    __syncthreads();

    for (int i = t; i < cnt; i += 256) {
        unsigned v = bucketbuf[start + i];
        int node = (v >> 16) & 255;
        int pos = atomicAdd(&lcur[node], 1);
        csr_src[start + pos] = (int)(v & 0xFFFFu);
    }
}

// ---------------- K5: per-node softmax + gather-aggregate (no atomics) ------
__global__ __launch_bounds__(256) void k5_node(
        const int* __restrict__ csr_src, const int* __restrict__ ends,
        const float* __restrict__ el, const float* __restrict__ er,
        const unsigned short* __restrict__ zb, float* __restrict__ out, int N) {
    const int lane = threadIdx.x & 63;
    const int node = blockIdx.x * 4 + (threadIdx.x >> 6);
    if (node >= N) return;

    const int start = (node == 0) ? 0 : ends[node - 1];
    const int end   = ends[node];
    const int deg   = end - start;
    float acc = 0.0f;

    if (deg > 0 && deg <= 64) {
        const float er_i = er[node];
        int   s0 = 0;
        float m  = -3.4e38f;
        float e0 = 0.0f;
        if (lane < deg) {
            s0 = csr_src[start + lane];
            float x = el[s0] + er_i;
            e0 = fmaxf(x, NEG_SLOPE * x);
            m  = e0;
        }
        #pragma unroll
        for (int msk = 32; msk; msk >>= 1) m = fmaxf(m, __shfl_xor(m, msk, 64));
        float ex0 = (lane < deg) ? __expf(e0 - m) : 0.0f;
        float sum = ex0;
        #pragma unroll
        for (int msk = 32; msk; msk >>= 1) sum += __shfl_xor(sum, msk, 64);
        const float inv = 1.0f / sum;

        float a0 = 0.f, a1 = 0.f, a2 = 0.f, a3 = 0.f;
        int r = 0;
        for (; r + 4 <= deg; r += 4) {
            int   sa = __shfl(s0,  r,     64), sb = __shfl(s0,  r + 1, 64);
            int   sc = __shfl(s0,  r + 2, 64), sd = __shfl(s0,  r + 3, 64);
            float wa = __shfl(ex0, r,     64), wb = __shfl(ex0, r + 1, 64);
            float wc = __shfl(ex0, r + 2, 64), wd = __shfl(ex0, r + 3, 64);
            float za = bf2f(zb[(size_t)sa * OUT_DIM + lane]);
            float zbv = bf2f(zb[(size_t)sb * OUT_DIM + lane]);
            float zc = bf2f(zb[(size_t)sc * OUT_DIM + lane]);
            float zd = bf2f(zb[(size_t)sd * OUT_DIM + lane]);
            a0 += wa * za; a1 += wb * zbv; a2 += wc * zc; a3 += wd * zd;
        }
        for (; r < deg; ++r) {
            int   sa = __shfl(s0,  r, 64);
            float wa = __shfl(ex0, r, 64);
            a0 += wa * bf2f(zb[(size_t)sa * OUT_DIM + lane]);
        }
        acc = ((a0 + a1) + (a2 + a3)) * inv;
    } else if (deg > 64) {
        const float er_i = er[node];
        float e0 = 0.0f, e1 = 0.0f;
        int   s0 = 0,    s1 = 0;
        float m = -3.4e38f;
        int t = 0;
        for (int j = start + lane; j < end; j += 64, ++t) {
            int s = csr_src[j];
            float x = el[s] + er_i;
            float e = fmaxf(x, NEG_SLOPE * x);
            if (t == 0) { e0 = e; s0 = s; }
            else if (t == 1) { e1 = e; s1 = s; }
            m = fmaxf(m, e);
        }
        #pragma unroll
        for (int msk = 32; msk; msk >>= 1) m = fmaxf(m, __shfl_xor(m, msk, 64));
        float sum = 0.0f;
        t = 0;
        for (int j = start + lane; j < end; j += 64, ++t) {
            float e;
            if (t == 0) e = e0;
            else if (t == 1) e = e1;
            else {
                int s = csr_src[j];
                float x = el[s] + er_i;
                e = fmaxf(x, NEG_SLOPE * x);
            }
            float ex = __expf(e - m);
            if (t == 0) e0 = ex; else if (t == 1) e1 = ex;
            sum += ex;
        }
        #pragma unroll
        for (int msk = 32; msk; msk >>= 1) sum += __shfl_xor(sum, msk, 64);
        const float inv = 1.0f / sum;

        for (int r = 0; r < deg; ++r) {
            int tt = r >> 6, owner = r & 63;
            int s; float ex;
            if (tt == 0)      { s = __shfl(s0, owner, 64); ex = __shfl(e0, owner, 64); }
            else if (tt == 1) { s = __shfl(s1, owner, 64); ex = __shfl(e1, owner, 64); }
            else {
                s = csr_src[start + r];
                float x = el[s] + er_i;
                float e = fmaxf(x, NEG_SLOPE * x);
                ex = __expf(e - m);
            }
            acc += ex * bf2f(zb[(size_t)s * OUT_DIM + lane]);
        }
        acc *= inv;
    }
    out[(size_t)node * OUT_DIM + lane] = acc;
}

extern "C" void kernel_launch(void* const* d_in, const int* in_sizes, int n_in,
                              void* d_out, int out_size, void* d_ws, size_t ws_size,
                              hipStream_t stream) {
    const float* h   = (const float*)d_in[0];
    const float* W   = (const float*)d_in[1];
    const float* a   = (const float*)d_in[2];
    const int*   src = (const int*)d_in[3];
    const int*   dst = (const int*)d_in[4];
    float* out = (float*)d_out;

    const int N = in_sizes[0] / IN_DIM;     // 50000
    const int E = in_sizes[3];              // 800000
    const int nbuck = (N + 255) >> 8;       // 196

    // workspace layout (~13.5 MB)
    unsigned short* zb = (unsigned short*)d_ws;          // N*64 bf16 (6.4 MB)
    float* el   = (float*)(zb + (size_t)N * OUT_DIM);    // N
    float* er   = el + N;                                // N
    int*   ends = (int*)(er + N);                        // N (global inclusive ends)
    int*   csr_src = ends + N;                           // E
    unsigned* bucketbuf = (unsigned*)(csr_src + E);      // E
    int*   bc     = (int*)(bucketbuf + E);               // nbuck
    int*   bstart = bc + 256;                            // nbuck+1
    int*   cursor = bstart + 257;                        // nbuck
    unsigned short* Wb = (unsigned short*)(cursor + 256); // 64*256 bf16 (32 KB)

    k_init<<<(OUT_DIM * IN_DIM + 255) / 256, 256, 0, stream>>>(W, Wb, bc, cursor, nbuck);
    {
        const int waves = (N + 15) / 16;    // 3125 row-tiles
        k1_mfma<<<(waves + 3) / 4, 256, 0, stream>>>(h, Wb, a, zb, el, er, N);
    }
    kA_count<<<512, 256, 0, stream>>>(dst, bc, E, nbuck);
    kA_scan<<<1, 256, 0, stream>>>(bc, bstart, nbuck);
    kA_scatter<<<(E + CHUNK - 1) / CHUNK, 256, 0, stream>>>(src, dst, bstart, cursor,
                                                            bucketbuf, E, nbuck);
    kB_build<<<nbuck, 256, 0, stream>>>(bucketbuf, bc, bstart, csr_src, ends, N);
    k5_node<<<(N + 3) / 4, 256, 0, stream>>>(csr_src, ends, el, er, zb, out, N);
}

// Round 7
// 104.982 us; speedup vs baseline: 4.0532x; 1.0251x over previous
//
#include <hip/hip_runtime.h>

#define IN_DIM 256
#define OUT_DIM 64
#define NEG_SLOPE 0.01f
#define CHUNK 4096   // edges per kA_scatter block

typedef __attribute__((ext_vector_type(8))) short short8v;   // 8 bf16 (4 VGPRs)
typedef __attribute__((ext_vector_type(4))) float float4v;   // MFMA C/D

// fp32 -> bf16 round-to-nearest-even
__device__ __forceinline__ unsigned short f2bf(float f) {
    unsigned u = __float_as_uint(f);
    return (unsigned short)((u + 0x7FFFu + ((u >> 16) & 1u)) >> 16);
}
__device__ __forceinline__ float bf2f(unsigned short u) {
    return __uint_as_float((unsigned)u << 16);
}

// ---------------- K0: zero bucket counters/cursors + convert W to bf16 -----
__global__ void k_init(const float* __restrict__ W, unsigned short* __restrict__ Wb,
                       int* __restrict__ bc, int* __restrict__ cursor) {
    int i = blockIdx.x * blockDim.x + threadIdx.x;
    if (i < OUT_DIM * IN_DIM) Wb[i] = f2bf(W[i]);
    if (i < 256) { bc[i] = 0; cursor[i] = 0; }
}

// ---------------- K1: MFMA projection + fused el/er + fused dst-count ------
// MFMA: one wave per 16-row tile, 4 x mfma_f32_16x16x32_bf16 (16 rows x 64
// cols). C/D layout (HW-verified): col = lane&15, row = (lane>>4)*4 + reg.
// Tail: all blocks grid-stride dst[] into an LDS histogram -> global bc.
// The count's memory traffic overlaps the MFMA phase of other blocks.
__global__ __launch_bounds__(256) void k1_mfma_count(
        const float* __restrict__ h, const unsigned short* __restrict__ Wb,
        const float* __restrict__ a, const int* __restrict__ dst,
        unsigned short* __restrict__ zb, float* __restrict__ el, float* __restrict__ er,
        int* __restrict__ bc, int M, int E) {
    __shared__ int hist[256];
    hist[threadIdx.x] = 0;

    const int lane = threadIdx.x & 63;
    const int wid  = (blockIdx.x * 256 + threadIdx.x) >> 6;
    const int r0 = wid * 16;

    if (r0 < M) {
        const int lrow = lane & 15;
        const int kgrp = lane >> 4;
        const int k0   = kgrp * 8;

        float4v acc[4];
        #pragma unroll
        for (int n = 0; n < 4; ++n) acc[n] = (float4v){0.f, 0.f, 0.f, 0.f};

        const float* __restrict__ hrow = h + (size_t)(r0 + lrow) * IN_DIM;

        #pragma unroll
        for (int step = 0; step < 8; ++step) {
            const int kk = step * 32 + k0;
            float4 ha = *(const float4*)(hrow + kk);
            float4 hb = *(const float4*)(hrow + kk + 4);
            short8v afrag;
            afrag[0] = (short)f2bf(ha.x); afrag[1] = (short)f2bf(ha.y);
            afrag[2] = (short)f2bf(ha.z); afrag[3] = (short)f2bf(ha.w);
            afrag[4] = (short)f2bf(hb.x); afrag[5] = (short)f2bf(hb.y);
            afrag[6] = (short)f2bf(hb.z); afrag[7] = (short)f2bf(hb.w);
            #pragma unroll
            for (int n = 0; n < 4; ++n) {
                short8v bfrag = *(const short8v*)(Wb + (size_t)(n * 16 + lrow) * IN_DIM + kk);
                acc[n] = __builtin_amdgcn_mfma_f32_16x16x32_bf16(afrag, bfrag, acc[n], 0, 0, 0);
            }
        }

        float al4[4], ar4[4];
        #pragma unroll
        for (int n = 0; n < 4; ++n) {
            al4[n] = a[n * 16 + lrow];
            ar4[n] = a[OUT_DIM + n * 16 + lrow];
        }
        #pragma unroll
        for (int j = 0; j < 4; ++j) {
            const int row = r0 + kgrp * 4 + j;
            float vl = 0.f, vr = 0.f;
            #pragma unroll
            for (int n = 0; n < 4; ++n) {
                float v = acc[n][j];
                zb[(size_t)row * OUT_DIM + n * 16 + lrow] = f2bf(v);
                vl += v * al4[n];
                vr += v * ar4[n];
            }
            #pragma unroll
            for (int m = 8; m >= 1; m >>= 1) {
                vl += __shfl_xor(vl, m, 64);
                vr += __shfl_xor(vr, m, 64);
            }
            if (lrow == 0) { el[row] = vl; er[row] = vr; }
        }
    }

    // ---- fused bucket count (bucket = dst>>8) ----
    __syncthreads();
    const int stride = gridDim.x * 256;
    for (int i = blockIdx.x * 256 + threadIdx.x; i < E; i += stride)
        atomicAdd(&hist[dst[i] >> 8], 1);
    __syncthreads();
    if (hist[threadIdx.x]) atomicAdd(&bc[threadIdx.x], hist[threadIdx.x]);
}

// ---------------- kA_scatter: partition edges into buckets, coalesced -------
// Self-computes bucket starts from bc (LDS scan). Per-block: LDS hist ->
// scan -> rank -> stage packed (dst<<16|src) in bucket order -> reserve
// global runs (1 atomic/bucket) -> coalesced run writes.
__global__ __launch_bounds__(256) void kA_scatter(
        const int* __restrict__ src, const int* __restrict__ dst,
        const int* __restrict__ bc, int* __restrict__ cursor,
        unsigned* __restrict__ bucketbuf, int E, int nbuck) {
    __shared__ unsigned stag[CHUNK];
    __shared__ int bsc[256], cnt[256], lofs[256], lcur[256], tb[256];
    const int t = threadIdx.x;
    const int base = blockIdx.x * CHUNK;
    const int n = min(CHUNK, E - base);

    // self-scan: bstart (exclusive prefix of bc) for this thread's bucket
    int bv = (t < nbuck) ? bc[t] : 0;
    bsc[t] = bv;
    cnt[t] = 0;
    __syncthreads();
    for (int off = 1; off < 256; off <<= 1) {
        int add = (t >= off) ? bsc[t - off] : 0;
        __syncthreads();
        bsc[t] += add;
        __syncthreads();
    }
    const int bstart_t = bsc[t] - bv;   // exclusive

    int es[16], ed[16];
    #pragma unroll
    for (int k = 0; k < 16; ++k) {
        int p = t + k * 256;
        if (p < n) {
            es[k] = src[base + p];
            ed[k] = dst[base + p];
            atomicAdd(&cnt[ed[k] >> 8], 1);
        }
    }
    __syncthreads();

    // exclusive scan of cnt -> lofs
    lofs[t] = cnt[t];
    __syncthreads();
    for (int off = 1; off < 256; off <<= 1) {
        int add = (t >= off) ? lofs[t - off] : 0;
        __syncthreads();
        lofs[t] += add;
        __syncthreads();
    }
    lofs[t] -= cnt[t];
    __syncthreads();

    // reserve global runs; translate staging position -> global
    {
        int c = cnt[t];
        int g = c ? atomicAdd(&cursor[t], c) : 0;
        tb[t] = bstart_t + g - lofs[t];
    }
    lcur[t] = lofs[t];
    __syncthreads();

    // rank + stage in bucket-sorted order
    #pragma unroll
    for (int k = 0; k < 16; ++k) {
        int p = t + k * 256;
        if (p < n) {
            int b = ed[k] >> 8;
            int pos = atomicAdd(&lcur[b], 1);
            stag[pos] = ((unsigned)ed[k] << 16) | (unsigned)es[k];
        }
    }
    __syncthreads();

    // coalesced run writes (consecutive p -> same bucket run)
    #pragma unroll
    for (int k = 0; k < 16; ++k) {
        int p = t + k * 256;
        if (p < n) {
            unsigned v = stag[p];
            int b = v >> 24;                 // = dst>>8
            bucketbuf[tb[b] + p] = v;
        }
    }
}

// ---------------- kB_build: per-bucket local CSR + ends --------------------
// One block per bucket (256 local nodes); self-computes its bucket start.
__global__ __launch_bounds__(256) void kB_build(
        const unsigned* __restrict__ bucketbuf, const int* __restrict__ bc,
        int* __restrict__ csr_src, int* __restrict__ ends, int N, int nbuck) {
    __shared__ int sc[256], lcnt[256], lofs[256], lcur[256];
    __shared__ int s_start;
    const int b = blockIdx.x, t = threadIdx.x;

    int bv = (t < nbuck) ? bc[t] : 0;
    sc[t] = bv;
    lcnt[t] = 0;
    __syncthreads();
    for (int off = 1; off < 256; off <<= 1) {
        int add = (t >= off) ? sc[t - off] : 0;
        __syncthreads();
        sc[t] += add;
        __syncthreads();
    }
    if (t == b) s_start = sc[t] - bv;       // exclusive prefix at own bucket
    __syncthreads();

    const int start = s_start;
    const int cnt = bc[b];
    const int node0 = b << 8;
    const int nloc = min(256, N - node0);

    for (int i = t; i < cnt; i += 256)
        atomicAdd(&lcnt[(bucketbuf[start + i] >> 16) & 255], 1);
    __syncthreads();

    // inclusive scan -> lofs
    lofs[t] = lcnt[t];
    __syncthreads();
    for (int off = 1; off < 256; off <<= 1) {
        int add = (t >= off) ? lofs[t - off] : 0;
        __syncthreads();
        lofs[t] += add;
        __syncthreads();
    }
    if (t < nloc) ends[node0 + t] = start + lofs[t];   // global inclusive end
    lcur[t] = lofs[t] - lcnt[t];                        // local exclusive start
    __syncthreads();

    for (int i = t; i < cnt; i += 256) {
        unsigned v = bucketbuf[start + i];
        int node = (v >> 16) & 255;
        int pos = atomicAdd(&lcur[node], 1);
        csr_src[start + pos] = (int)(v & 0xFFFFu);
    }
}

// ---------------- K5: per-node softmax + gather-aggregate (no atomics) ------
// One wave per dst node; fast path (deg<=64) 8-way unrolled gather.
__global__ __launch_bounds__(256) void k5_node(
        const int* __restrict__ csr_src, const int* __restrict__ ends,
        const float* __restrict__ el, const float* __restrict__ er,
        const unsigned short* __restrict__ zb, float* __restrict__ out, int N) {
    const int lane = threadIdx.x & 63;
    const int node = blockIdx.x * 4 + (threadIdx.x >> 6);
    if (node >= N) return;

    const int start = (node == 0) ? 0 : ends[node - 1];
    const int end   = ends[node];
    const int deg   = end - start;
    float acc = 0.0f;

    if (deg > 0 && deg <= 64) {
        const float er_i = er[node];
        int   s0 = 0;
        float m  = -3.4e38f;
        float e0 = 0.0f;
        if (lane < deg) {
            s0 = csr_src[start + lane];
            float x = el[s0] + er_i;
            e0 = fmaxf(x, NEG_SLOPE * x);
            m  = e0;
        }
        #pragma unroll
        for (int msk = 32; msk; msk >>= 1) m = fmaxf(m, __shfl_xor(m, msk, 64));
        float ex0 = (lane < deg) ? __expf(e0 - m) : 0.0f;
        float sum = ex0;
        #pragma unroll
        for (int msk = 32; msk; msk >>= 1) sum += __shfl_xor(sum, msk, 64);
        const float inv = 1.0f / sum;

        float aq[8];
        #pragma unroll
        for (int q = 0; q < 8; ++q) aq[q] = 0.f;
        int r = 0;
        for (; r + 8 <= deg; r += 8) {
            int ss[8]; float ww[8];
            #pragma unroll
            for (int q = 0; q < 8; ++q) {
                ss[q] = __shfl(s0,  r + q, 64);
                ww[q] = __shfl(ex0, r + q, 64);
            }
            #pragma unroll
            for (int q = 0; q < 8; ++q)
                aq[q] += ww[q] * bf2f(zb[(size_t)ss[q] * OUT_DIM + lane]);
        }
        for (; r < deg; ++r) {
            int   sa = __shfl(s0,  r, 64);
            float wa = __shfl(ex0, r, 64);
            aq[0] += wa * bf2f(zb[(size_t)sa * OUT_DIM + lane]);
        }
        acc = (((aq[0] + aq[1]) + (aq[2] + aq[3])) +
               ((aq[4] + aq[5]) + (aq[6] + aq[7]))) * inv;
    } else if (deg > 64) {
        const float er_i = er[node];
        float e0 = 0.0f, e1 = 0.0f;
        int   s0 = 0,    s1 = 0;
        float m = -3.4e38f;
        int t = 0;
        for (int j = start + lane; j < end; j += 64, ++t) {
            int s = csr_src[j];
            float x = el[s] + er_i;
            float e = fmaxf(x, NEG_SLOPE * x);
            if (t == 0) { e0 = e; s0 = s; }
            else if (t == 1) { e1 = e; s1 = s; }
            m = fmaxf(m, e);
        }
        #pragma unroll
        for (int msk = 32; msk; msk >>= 1) m = fmaxf(m, __shfl_xor(m, msk, 64));
        float sum = 0.0f;
        t = 0;
        for (int j = start + lane; j < end; j += 64, ++t) {
            float e;
            if (t == 0) e = e0;
            else if (t == 1) e = e1;
            else {
                int s = csr_src[j];
                float x = el[s] + er_i;
                e = fmaxf(x, NEG_SLOPE * x);
            }
            float ex = __expf(e - m);
            if (t == 0) e0 = ex; else if (t == 1) e1 = ex;
            sum += ex;
        }
        #pragma unroll
        for (int msk = 32; msk; msk >>= 1) sum += __shfl_xor(sum, msk, 64);
        const float inv = 1.0f / sum;

        for (int r = 0; r < deg; ++r) {
            int tt = r >> 6, owner = r & 63;
            int s; float ex;
            if (tt == 0)      { s = __shfl(s0, owner, 64); ex = __shfl(e0, owner, 64); }
            else if (tt == 1) { s = __shfl(s1, owner, 64); ex = __shfl(e1, owner, 64); }
            else {
                s = csr_src[start + r];
                float x = el[s] + er_i;
                float e = fmaxf(x, NEG_SLOPE * x);
                ex = __expf(e - m);
            }
            acc += ex * bf2f(zb[(size_t)s * OUT_DIM + lane]);
        }
        acc *= inv;
    }
    out[(size_t)node * OUT_DIM + lane] = acc;
}

extern "C" void kernel_launch(void* const* d_in, const int* in_sizes, int n_in,
                              void* d_out, int out_size, void* d_ws, size_t ws_size,
                              hipStream_t stream) {
    const float* h   = (const float*)d_in[0];
    const float* W   = (const float*)d_in[1];
    const float* a   = (const float*)d_in[2];
    const int*   src = (const int*)d_in[3];
    const int*   dst = (const int*)d_in[4];
    float* out = (float*)d_out;

    const int N = in_sizes[0] / IN_DIM;     // 50000
    const int E = in_sizes[3];              // 800000
    const int nbuck = (N + 255) >> 8;       // 196

    // workspace layout (~13.4 MB)
    unsigned short* zb = (unsigned short*)d_ws;          // N*64 bf16 (6.4 MB)
    float* el   = (float*)(zb + (size_t)N * OUT_DIM);    // N
    float* er   = el + N;                                // N
    int*   ends = (int*)(er + N);                        // N (global inclusive ends)
    int*   csr_src = ends + N;                           // E
    unsigned* bucketbuf = (unsigned*)(csr_src + E);      // E
    int*   bc     = (int*)(bucketbuf + E);               // 256
    int*   cursor = bc + 256;                            // 256
    unsigned short* Wb = (unsigned short*)(cursor + 256); // 64*256 bf16 (32 KB)

    k_init<<<(OUT_DIM * IN_DIM + 255) / 256, 256, 0, stream>>>(W, Wb, bc, cursor);
    {
        const int waves = (N + 15) / 16;    // 3125 row-tiles
        k1_mfma_count<<<(waves + 3) / 4, 256, 0, stream>>>(h, Wb, a, dst, zb, el, er,
                                                           bc, N, E);
    }
    kA_scatter<<<(E + CHUNK - 1) / CHUNK, 256, 0, stream>>>(src, dst, bc, cursor,
                                                            bucketbuf, E, nbuck);
    kB_build<<<nbuck, 256, 0, stream>>>(bucketbuf, bc, csr_src, ends, N, nbuck);
    k5_node<<<(N + 3) / 4, 256, 0, stream>>>(csr_src, ends, el, er, zb, out, N);
}

// Round 8
// 95.419 us; speedup vs baseline: 4.4595x; 1.1002x over previous
//
#include <hip/hip_runtime.h>

#define IN_DIM 256
#define OUT_DIM 64
#define NEG_SLOPE 0.01f
#define CHUNK 4096   // edges per kA_scatter block

typedef __attribute__((ext_vector_type(8))) short short8v;   // 8 bf16 (4 VGPRs)
typedef __attribute__((ext_vector_type(4))) float float4v;   // MFMA C/D

// fp32 -> bf16 round-to-nearest-even
__device__ __forceinline__ unsigned short f2bf(float f) {
    unsigned u = __float_as_uint(f);
    return (unsigned short)((u + 0x7FFFu + ((u >> 16) & 1u)) >> 16);
}
__device__ __forceinline__ float bf2f(unsigned short u) {
    return __uint_as_float((unsigned)u << 16);
}

// ---------------- K0: zero bucket counters/cursors + convert W to bf16 -----
__global__ void k_init(const float* __restrict__ W, unsigned short* __restrict__ Wb,
                       int* __restrict__ bc, int* __restrict__ cursor) {
    int i = blockIdx.x * blockDim.x + threadIdx.x;
    if (i < OUT_DIM * IN_DIM) Wb[i] = f2bf(W[i]);
    if (i < 256) { bc[i] = 0; cursor[i] = 0; }
}

// ---------------- K1: MFMA projection + fused el/er + fused dst-count ------
// One wave per 16-row tile, 4 x mfma_f32_16x16x32_bf16 (16 rows x 64 cols).
// C/D layout (HW-verified): col = lane&15, row = (lane>>4)*4 + reg.
// Latency fixes (R7): (a) all 16 h-float4 preloaded into regs -> 16 loads in
// flight; (b) Wb staged in LDS with 16B-slot XOR swizzle -> ds_read_b128 at
// the 8-access/bank minimum, no L1 thrash.
__global__ __launch_bounds__(256, 3) void k1_mfma_count(
        const float* __restrict__ h, const unsigned short* __restrict__ Wb,
        const float* __restrict__ a, const int* __restrict__ dst,
        unsigned short* __restrict__ zb, float* __restrict__ el, float* __restrict__ er,
        int* __restrict__ bc, int M, int E) {
    __shared__ uint4 wlds[2048];          // 32 KB: W bf16, swizzled 16B slots
    __shared__ int hist[256];
    hist[threadIdx.x] = 0;

    // stage Wb -> LDS: slot = row*32 + (col ^ (row&7)); coalesced global read
    #pragma unroll
    for (int k = 0; k < 8; ++k) {
        int c = threadIdx.x + k * 256;
        int row = c >> 5, col = c & 31;
        wlds[(row << 5) | (col ^ (row & 7))] = ((const uint4*)Wb)[c];
    }
    __syncthreads();

    const int lane = threadIdx.x & 63;
    const int wid  = (blockIdx.x * 256 + threadIdx.x) >> 6;
    const int r0 = wid * 16;

    if (r0 < M) {
        const int lrow = lane & 15;
        const int kgrp = lane >> 4;
        const int k0   = kgrp * 8;
        const int swz  = lrow & 7;

        const float* __restrict__ hrow = h + (size_t)(r0 + lrow) * IN_DIM;

        // burst-load the whole per-lane h strip (16 x dwordx4 in flight)
        float4 hreg[16];
        #pragma unroll
        for (int s = 0; s < 8; ++s) {
            hreg[2 * s]     = *(const float4*)(hrow + s * 32 + k0);
            hreg[2 * s + 1] = *(const float4*)(hrow + s * 32 + k0 + 4);
        }

        float4v acc[4];
        #pragma unroll
        for (int n = 0; n < 4; ++n) acc[n] = (float4v){0.f, 0.f, 0.f, 0.f};

        #pragma unroll
        for (int s = 0; s < 8; ++s) {
            float4 ha = hreg[2 * s], hb = hreg[2 * s + 1];
            short8v afrag;
            afrag[0] = (short)f2bf(ha.x); afrag[1] = (short)f2bf(ha.y);
            afrag[2] = (short)f2bf(ha.z); afrag[3] = (short)f2bf(ha.w);
            afrag[4] = (short)f2bf(hb.x); afrag[5] = (short)f2bf(hb.y);
            afrag[6] = (short)f2bf(hb.z); afrag[7] = (short)f2bf(hb.w);
            #pragma unroll
            for (int n = 0; n < 4; ++n) {
                const int slot = ((n * 16 + lrow) << 5) | ((s * 4 + kgrp) ^ swz);
                short8v bfrag = *(const short8v*)&wlds[slot];
                acc[n] = __builtin_amdgcn_mfma_f32_16x16x32_bf16(afrag, bfrag, acc[n], 0, 0, 0);
            }
        }

        float al4[4], ar4[4];
        #pragma unroll
        for (int n = 0; n < 4; ++n) {
            al4[n] = a[n * 16 + lrow];
            ar4[n] = a[OUT_DIM + n * 16 + lrow];
        }
        #pragma unroll
        for (int j = 0; j < 4; ++j) {
            const int row = r0 + kgrp * 4 + j;
            float vl = 0.f, vr = 0.f;
            #pragma unroll
            for (int n = 0; n < 4; ++n) {
                float v = acc[n][j];
                zb[(size_t)row * OUT_DIM + n * 16 + lrow] = f2bf(v);
                vl += v * al4[n];
                vr += v * ar4[n];
            }
            #pragma unroll
            for (int m = 8; m >= 1; m >>= 1) {
                vl += __shfl_xor(vl, m, 64);
                vr += __shfl_xor(vr, m, 64);
            }
            if (lrow == 0) { el[row] = vl; er[row] = vr; }
        }
    }

    // ---- fused bucket count (bucket = dst>>8) ----
    __syncthreads();
    const int stride = gridDim.x * 256;
    for (int i = blockIdx.x * 256 + threadIdx.x; i < E; i += stride)
        atomicAdd(&hist[dst[i] >> 8], 1);
    __syncthreads();
    if (hist[threadIdx.x]) atomicAdd(&bc[threadIdx.x], hist[threadIdx.x]);
}

// ---------------- kA_scatter: partition edges into buckets, coalesced -------
// Self-computes bucket starts from bc (LDS scan). Per-block: LDS hist ->
// scan -> rank -> stage packed (dst<<16|src) in bucket order -> reserve
// global runs (1 atomic/bucket) -> coalesced run writes.
__global__ __launch_bounds__(256) void kA_scatter(
        const int* __restrict__ src, const int* __restrict__ dst,
        const int* __restrict__ bc, int* __restrict__ cursor,
        unsigned* __restrict__ bucketbuf, int E, int nbuck) {
    __shared__ unsigned stag[CHUNK];
    __shared__ int bsc[256], cnt[256], lofs[256], lcur[256], tb[256];
    const int t = threadIdx.x;
    const int base = blockIdx.x * CHUNK;
    const int n = min(CHUNK, E - base);

    // self-scan: bstart (exclusive prefix of bc) for this thread's bucket
    int bv = (t < nbuck) ? bc[t] : 0;
    bsc[t] = bv;
    cnt[t] = 0;
    __syncthreads();
    for (int off = 1; off < 256; off <<= 1) {
        int add = (t >= off) ? bsc[t - off] : 0;
        __syncthreads();
        bsc[t] += add;
        __syncthreads();
    }
    const int bstart_t = bsc[t] - bv;   // exclusive

    int es[16], ed[16];
    #pragma unroll
    for (int k = 0; k < 16; ++k) {
        int p = t + k * 256;
        if (p < n) {
            es[k] = src[base + p];
            ed[k] = dst[base + p];
            atomicAdd(&cnt[ed[k] >> 8], 1);
        }
    }
    __syncthreads();

    // exclusive scan of cnt -> lofs
    lofs[t] = cnt[t];
    __syncthreads();
    for (int off = 1; off < 256; off <<= 1) {
        int add = (t >= off) ? lofs[t - off] : 0;
        __syncthreads();
        lofs[t] += add;
        __syncthreads();
    }
    lofs[t] -= cnt[t];
    __syncthreads();

    // reserve global runs; translate staging position -> global
    {
        int c = cnt[t];
        int g = c ? atomicAdd(&cursor[t], c) : 0;
        tb[t] = bstart_t + g - lofs[t];
    }
    lcur[t] = lofs[t];
    __syncthreads();

    // rank + stage in bucket-sorted order
    #pragma unroll
    for (int k = 0; k < 16; ++k) {
        int p = t + k * 256;
        if (p < n) {
            int b = ed[k] >> 8;
            int pos = atomicAdd(&lcur[b], 1);
            stag[pos] = ((unsigned)ed[k] << 16) | (unsigned)es[k];
        }
    }
    __syncthreads();

    // coalesced run writes (consecutive p -> same bucket run)
    #pragma unroll
    for (int k = 0; k < 16; ++k) {
        int p = t + k * 256;
        if (p < n) {
            unsigned v = stag[p];
            int b = v >> 24;                 // = dst>>8
            bucketbuf[tb[b] + p] = v;
        }
    }
}

// ---------------- kB_build: per-bucket local CSR + ends --------------------
// One block per bucket (256 local nodes); self-computes its bucket start.
__global__ __launch_bounds__(256) void kB_build(
        const unsigned* __restrict__ bucketbuf, const int* __restrict__ bc,
        int* __restrict__ csr_src, int* __restrict__ ends, int N, int nbuck) {
    __shared__ int sc[256], lcnt[256], lofs[256], lcur[256];
    __shared__ int s_start;
    const int b = blockIdx.x, t = threadIdx.x;

    int bv = (t < nbuck) ? bc[t] : 0;
    sc[t] = bv;
    lcnt[t] = 0;
    __syncthreads();
    for (int off = 1; off < 256; off <<= 1) {
        int add = (t >= off) ? sc[t - off] : 0;
        __syncthreads();
        sc[t] += add;
        __syncthreads();
    }
    if (t == b) s_start = sc[t] - bv;       // exclusive prefix at own bucket
    __syncthreads();

    const int start = s_start;
    const int cnt = bc[b];
    const int node0 = b << 8;
    const int nloc = min(256, N - node0);

    for (int i = t; i < cnt; i += 256)
        atomicAdd(&lcnt[(bucketbuf[start + i] >> 16) & 255], 1);
    __syncthreads();

    // inclusive scan -> lofs
    lofs[t] = lcnt[t];
    __syncthreads();
    for (int off = 1; off < 256; off <<= 1) {
        int add = (t >= off) ? lofs[t - off] : 0;
        __syncthreads();
        lofs[t] += add;
        __syncthreads();
    }
    if (t < nloc) ends[node0 + t] = start + lofs[t];   // global inclusive end
    lcur[t] = lofs[t] - lcnt[t];                        // local exclusive start
    __syncthreads();

    for (int i = t; i < cnt; i += 256) {
        unsigned v = bucketbuf[start + i];
        int node = (v >> 16) & 255;
        int pos = atomicAdd(&lcur[node], 1);
        csr_src[start + pos] = (int)(v & 0xFFFFu);
    }
}

// ---------------- K5: per-node softmax + gather-aggregate (no atomics) ------
// One wave per dst node; fast path (deg<=64) 8-way unrolled gather.
__global__ __launch_bounds__(256) void k5_node(
        const int* __restrict__ csr_src, const int* __restrict__ ends,
        const float* __restrict__ el, const float* __restrict__ er,
        const unsigned short* __restrict__ zb, float* __restrict__ out, int N) {
    const int lane = threadIdx.x & 63;
    const int node = blockIdx.x * 4 + (threadIdx.x >> 6);
    if (node >= N) return;

    const int start = (node == 0) ? 0 : ends[node - 1];
    const int end   = ends[node];
    const int deg   = end - start;
    float acc = 0.0f;

    if (deg > 0 && deg <= 64) {
        const float er_i = er[node];
        int   s0 = 0;
        float m  = -3.4e38f;
        float e0 = 0.0f;
        if (lane < deg) {
            s0 = csr_src[start + lane];
            float x = el[s0] + er_i;
            e0 = fmaxf(x, NEG_SLOPE * x);
            m  = e0;
        }
        #pragma unroll
        for (int msk = 32; msk; msk >>= 1) m = fmaxf(m, __shfl_xor(m, msk, 64));
        float ex0 = (lane < deg) ? __expf(e0 - m) : 0.0f;
        float sum = ex0;
        #pragma unroll
        for (int msk = 32; msk; msk >>= 1) sum += __shfl_xor(sum, msk, 64);
        const float inv = 1.0f / sum;

        float aq[8];
        #pragma unroll
        for (int q = 0; q < 8; ++q) aq[q] = 0.f;
        int r = 0;
        for (; r + 8 <= deg; r += 8) {
            int ss[8]; float ww[8];
            #pragma unroll
            for (int q = 0; q < 8; ++q) {
                ss[q] = __shfl(s0,  r + q, 64);
                ww[q] = __shfl(ex0, r + q, 64);
            }
            #pragma unroll
            for (int q = 0; q < 8; ++q)
                aq[q] += ww[q] * bf2f(zb[(size_t)ss[q] * OUT_DIM + lane]);
        }
        for (; r < deg; ++r) {
            int   sa = __shfl(s0,  r, 64);
            float wa = __shfl(ex0, r, 64);
            aq[0] += wa * bf2f(zb[(size_t)sa * OUT_DIM + lane]);
        }
        acc = (((aq[0] + aq[1]) + (aq[2] + aq[3])) +
               ((aq[4] + aq[5]) + (aq[6] + aq[7]))) * inv;
    } else if (deg > 64) {
        const float er_i = er[node];
        float e0 = 0.0f, e1 = 0.0f;
        int   s0 = 0,    s1 = 0;
        float m = -3.4e38f;
        int t = 0;
        for (int j = start + lane; j < end; j += 64, ++t) {
            int s = csr_src[j];
            float x = el[s] + er_i;
            float e = fmaxf(x, NEG_SLOPE * x);
            if (t == 0) { e0 = e; s0 = s; }
            else if (t == 1) { e1 = e; s1 = s; }
            m = fmaxf(m, e);
        }
        #pragma unroll
        for (int msk = 32; msk; msk >>= 1) m = fmaxf(m, __shfl_xor(m, msk, 64));
        float sum = 0.0f;
        t = 0;
        for (int j = start + lane; j < end; j += 64, ++t) {
            float e;
            if (t == 0) e = e0;
            else if (t == 1) e = e1;
            else {
                int s = csr_src[j];
                float x = el[s] + er_i;
                e = fmaxf(x, NEG_SLOPE * x);
            }
            float ex = __expf(e - m);
            if (t == 0) e0 = ex; else if (t == 1) e1 = ex;
            sum += ex;
        }
        #pragma unroll
        for (int msk = 32; msk; msk >>= 1) sum += __shfl_xor(sum, msk, 64);
        const float inv = 1.0f / sum;

        for (int r = 0; r < deg; ++r) {
            int tt = r >> 6, owner = r & 63;
            int s; float ex;
            if (tt == 0)      { s = __shfl(s0, owner, 64); ex = __shfl(e0, owner, 64); }
            else if (tt == 1) { s = __shfl(s1, owner, 64); ex = __shfl(e1, owner, 64); }
            else {
                s = csr_src[start + r];
                float x = el[s] + er_i;
                float e = fmaxf(x, NEG_SLOPE * x);
                ex = __expf(e - m);
            }
            acc += ex * bf2f(zb[(size_t)s * OUT_DIM + lane]);
        }
        acc *= inv;
    }
    out[(size_t)node * OUT_DIM + lane] = acc;
}

extern "C" void kernel_launch(void* const* d_in, const int* in_sizes, int n_in,
                              void* d_out, int out_size, void* d_ws, size_t ws_size,
                              hipStream_t stream) {
    const float* h   = (const float*)d_in[0];
    const float* W   = (const float*)d_in[1];
    const float* a   = (const float*)d_in[2];
    const int*   src = (const int*)d_in[3];
    const int*   dst = (const int*)d_in[4];
    float* out = (float*)d_out;

    const int N = in_sizes[0] / IN_DIM;     // 50000
    const int E = in_sizes[3];              // 800000
    const int nbuck = (N + 255) >> 8;       // 196

    // workspace layout (~13.4 MB)
    unsigned short* zb = (unsigned short*)d_ws;          // N*64 bf16 (6.4 MB)
    float* el   = (float*)(zb + (size_t)N * OUT_DIM);    // N
    float* er   = el + N;                                // N
    int*   ends = (int*)(er + N);                        // N (global inclusive ends)
    int*   csr_src = ends + N;                           // E
    unsigned* bucketbuf = (unsigned*)(csr_src + E);      // E
    int*   bc     = (int*)(bucketbuf + E);               // 256
    int*   cursor = bc + 256;                            // 256
    unsigned short* Wb = (unsigned short*)(cursor + 256); // 64*256 bf16 (32 KB, 16B-aligned)

    k_init<<<(OUT_DIM * IN_DIM + 255) / 256, 256, 0, stream>>>(W, Wb, bc, cursor);
    {
        const int waves = (N + 15) / 16;    // 3125 row-tiles
        k1_mfma_count<<<(waves + 3) / 4, 256, 0, stream>>>(h, Wb, a, dst, zb, el, er,
                                                           bc, N, E);
    }
    kA_scatter<<<(E + CHUNK - 1) / CHUNK, 256, 0, stream>>>(src, dst, bc, cursor,
                                                            bucketbuf, E, nbuck);
    kB_build<<<nbuck, 256, 0, stream>>>(bucketbuf, bc, csr_src, ends, N, nbuck);
    k5_node<<<(N + 3) / 4, 256, 0, stream>>>(csr_src, ends, el, er, zb, out, N);
}